// Round 1
// baseline (457.899 us; speedup 1.0000x reference)
//
#include <hip/hip_runtime.h>
#include <hip/hip_bf16.h>

#define B_ 4
#define S_ 4096
#define D_ 1024
#define NT_ 32        // S_/128
#define PAIRS_ 528    // NT_*(NT_+1)/2 lower-triangle tile pairs

typedef __attribute__((ext_vector_type(8))) short short8;
typedef __attribute__((ext_vector_type(4))) float f32x4;

__device__ __forceinline__ unsigned short f2bf(float f) {
    union { float f; unsigned u; } v; v.f = f;
    unsigned u = v.u;
    return (unsigned short)((u + 0x7fffu + ((u >> 16) & 1u)) >> 16);
}

// async global->LDS, 16B per lane. LDS dst is wave-uniform base + lane*16.
__device__ __forceinline__ void gld_lds16(const unsigned short* g, unsigned short* l) {
    __builtin_amdgcn_global_load_lds((const __attribute__((address_space(1))) void*)g,
                                     (__attribute__((address_space(3))) void*)l, 16, 0, 0);
}

// stage a 128x32 bf16 tile (global row stride = ld elems) into contiguous LDS [128][32]
__device__ __forceinline__ void stage128x32(const unsigned short* gbase, size_t ld,
                                            unsigned short* ls, int tid) {
    const int r = tid >> 2;
    const int c = (tid & 3) * 8;
    unsigned short* lw = ls + tid * 8;
    gld_lds16(gbase + (size_t)r * ld + c, lw);
    gld_lds16(gbase + (size_t)(r + 64) * ld + c, lw + 2048);
}

// ---------------------------------------------------------------------------
// prep_x: fp32 x -> bf16 xb
// ---------------------------------------------------------------------------
__global__ __launch_bounds__(256) void prep_x(const float* __restrict__ x,
                                              unsigned short* __restrict__ xb) {
    size_t i = ((size_t)blockIdx.x * 256 + threadIdx.x) * 8;
    float4 a = *(const float4*)&x[i];
    float4 b = *(const float4*)&x[i + 4];
    unsigned u0 = (unsigned)f2bf(a.x) | ((unsigned)f2bf(a.y) << 16);
    unsigned u1 = (unsigned)f2bf(a.z) | ((unsigned)f2bf(a.w) << 16);
    unsigned u2 = (unsigned)f2bf(b.x) | ((unsigned)f2bf(b.y) << 16);
    unsigned u3 = (unsigned)f2bf(b.z) | ((unsigned)f2bf(b.w) << 16);
    uint4 val; val.x = u0; val.y = u1; val.z = u2; val.w = u3;
    *(uint4*)&xb[i] = val;
}

// ---------------------------------------------------------------------------
// prep_w: W[k][n] fp32 -> Wt[n][k] bf16
// ---------------------------------------------------------------------------
__global__ __launch_bounds__(256) void prep_w(const float* __restrict__ Wq,
                                              const float* __restrict__ Wk,
                                              const float* __restrict__ Wv,
                                              unsigned short* __restrict__ Wt) {
    __shared__ float ls[64 * 65];
    const int z = blockIdx.z;
    const float* __restrict__ W = (z == 0) ? Wq : (z == 1) ? Wk : Wv;
    unsigned short* __restrict__ Wtz = Wt + (size_t)z * D_ * D_;
    const int k0 = blockIdx.y * 64, n0 = blockIdx.x * 64;
    const int tid = threadIdx.x;
    #pragma unroll
    for (int i = 0; i < 16; ++i) {
        int lin = i * 256 + tid, r = lin >> 6, c = lin & 63;
        ls[r * 65 + c] = W[(size_t)(k0 + r) * D_ + n0 + c];
    }
    __syncthreads();
    #pragma unroll
    for (int i = 0; i < 16; ++i) {
        int lin = i * 256 + tid, r = lin >> 6, c = lin & 63;
        Wtz[(size_t)(n0 + r) * D_ + k0 + c] = f2bf(ls[c * 65 + r]);
    }
}

// ---------------------------------------------------------------------------
// qkv_gemm: Y = xb @ Wt_z^T.
// 256x256 tile, BK=64, 8 waves (2Mx4N), 8-phase schedule (T3+T4), st-swizzled
// LDS (T2, via inverse-swizzled global source + swizzled ds_read), setprio
// around MFMA clusters (T5). Counted vmcnt: steady-state boundary wait is
// vmcnt(4) (the 2 half-tiles of K-tile t+2 staged in phase 3 stay in flight).
// Schedule per K-tile t (buf = t&1):
//   ph0: LDA(half0)+LDB(half0) | STAGE(t+1, Bhalf0 -> buf^1) | bar | MFMA(0,0) | bar
//   ph1: LDB(half1)            | STAGE(t+1, Bhalf1 -> buf^1) | bar | MFMA(0,1) | bar
//   ph2: LDA(half1)            |                             | bar | MFMA(1,1) | bar
//   ph3: LDB(half0)            | STAGE(t+2, Ahalf0+Ahalf1 -> buf; A-region of
//        buf is dead after ph2's lgkmcnt(0))  | bar | MFMA(1,0) | vmcnt(4) | bar
// Halves of t+1's A were staged at (t-1, ph3); halves of t+1's B at (t, ph0/1).
// ---------------------------------------------------------------------------
__global__ __launch_bounds__(512, 2) void qkv_gemm(
    const unsigned short* __restrict__ xb, const unsigned short* __restrict__ Wt,
    unsigned short* __restrict__ Q, unsigned short* __restrict__ K,
    unsigned short* __restrict__ V)
{
    __shared__ __align__(16) unsigned short lsA[2 * 256 * 64];   // 64 KiB
    __shared__ __align__(16) unsigned short lsB[2 * 256 * 64];   // 64 KiB

    const int z = blockIdx.z;
    unsigned short* __restrict__ Y = (z == 0) ? Q : (z == 1) ? K : V;
    const float scale = (z == 0) ? 0.03125f : 1.0f;

    // XCD-aware swizzle: 256 wgs, 8 XCDs, 32 contiguous wgs per XCD, n-inner.
    const int lin = blockIdx.x;                       // 0..255
    const int wg = (lin & 7) * 32 + (lin >> 3);
    const int m0 = (wg >> 2) * 256, n0 = (wg & 3) * 256;

    const int tid = threadIdx.x, lane = tid & 63, w = tid >> 6;
    const int wm = w >> 2, wn = w & 3;                // 2 x 4 wave grid
    const int quad = lane >> 4, ln = lane & 15;

    const unsigned short* Ab = xb + (size_t)m0 * D_;
    const unsigned short* Bb = Wt + (size_t)z * D_ * D_ + (size_t)n0 * D_;

    // Stage one 128x64 half-tile. Dest is LINEAR (global_load_lds constraint);
    // the XOR-16B-granule swizzle is applied on the SOURCE column so that the
    // swizzled ds_read below finds (row r, col-granule cg) at
    // byte (r*128) ^ (((cg^(r&7)))*16).  granule g: row=g>>3, src colg=(g&7)^(row&7).
#define STAGE_HALF(gbase, ldsbase)                                              \
    {                                                                           \
        _Pragma("unroll")                                                       \
        for (int i_ = 0; i_ < 2; ++i_) {                                        \
            int g_ = tid + i_ * 512;                                            \
            int r_ = g_ >> 3;                                                   \
            int cg_ = (g_ & 7) ^ (r_ & 7);                                      \
            gld_lds16((gbase) + (size_t)r_ * D_ + cg_ * 8, (ldsbase) + g_ * 8); \
        }                                                                       \
    }
    // half h: 0=A rows0..127, 1=A rows128..255, 2=B rows0..127, 3=B rows128..255
#define STAGE(kt, h)                                                                   \
    {                                                                                  \
        if ((h) < 2) { STAGE_HALF(Ab + (size_t)((h) * 128) * D_ + (kt) * 64,           \
                                  &lsA[(((kt) & 1) * 2 + (h)) * 8192]) }               \
        else         { STAGE_HALF(Bb + (size_t)(((h) - 2) * 128) * D_ + (kt) * 64,     \
                                  &lsB[(((kt) & 1) * 2 + ((h) - 2)) * 8192]) }         \
    }

    const unsigned short* As;
    const unsigned short* Bs;
    short8 a[4][2], b[2][2];
    f32x4 acc[8][4] = {};

#define LDA(mh)                                                                        \
    {                                                                                  \
        _Pragma("unroll")                                                              \
        for (int mf_ = 0; mf_ < 4; ++mf_) {                                            \
            _Pragma("unroll")                                                          \
            for (int ks_ = 0; ks_ < 2; ++ks_) {                                        \
                int r_ = wm * 128 + ((mh) * 4 + mf_) * 16 + ln;                        \
                int cg_ = ks_ * 4 + quad;                                              \
                a[mf_][ks_] = *(const short8*)&As[r_ * 64 + ((cg_ ^ (r_ & 7)) << 3)];  \
            }                                                                          \
        }                                                                              \
    }
#define LDB(nh)                                                                        \
    {                                                                                  \
        _Pragma("unroll")                                                              \
        for (int nf_ = 0; nf_ < 2; ++nf_) {                                            \
            _Pragma("unroll")                                                          \
            for (int ks_ = 0; ks_ < 2; ++ks_) {                                        \
                int r_ = wn * 64 + ((nh) * 2 + nf_) * 16 + ln;                         \
                int cg_ = ks_ * 4 + quad;                                              \
                b[nf_][ks_] = *(const short8*)&Bs[r_ * 64 + ((cg_ ^ (r_ & 7)) << 3)];  \
            }                                                                          \
        }                                                                              \
    }
#define MM(mh, nh)                                                                     \
    {                                                                                  \
        __builtin_amdgcn_s_setprio(1);                                                 \
        _Pragma("unroll")                                                              \
        for (int mf_ = 0; mf_ < 4; ++mf_)                                              \
            _Pragma("unroll")                                                          \
            for (int nf_ = 0; nf_ < 2; ++nf_)                                          \
                _Pragma("unroll")                                                      \
                for (int ks_ = 0; ks_ < 2; ++ks_)                                      \
                    acc[(mh) * 4 + mf_][(nh) * 2 + nf_] =                              \
                        __builtin_amdgcn_mfma_f32_16x16x32_bf16(                       \
                            a[mf_][ks_], b[nf_][ks_],                                  \
                            acc[(mh) * 4 + mf_][(nh) * 2 + nf_], 0, 0, 0);             \
        __builtin_amdgcn_s_setprio(0);                                                 \
    }
#define LGKM0 asm volatile("s_waitcnt lgkmcnt(0)" ::: "memory")
#define BAR   __builtin_amdgcn_s_barrier()

    // prologue: full K-tile 0 + A-halves of K-tile 1 in flight
    STAGE(0, 0) STAGE(0, 1) STAGE(0, 2) STAGE(0, 3)
    STAGE(1, 0) STAGE(1, 1)
    asm volatile("s_waitcnt vmcnt(4)" ::: "memory");
    BAR;

    #pragma unroll 2
    for (int t = 0; t < 16; ++t) {
        As = lsA + (t & 1) * 16384;
        Bs = lsB + (t & 1) * 16384;
        // phase 0: quadrant (0,0)
        LDA(0) LDB(0)
        if (t < 15) STAGE(t + 1, 2)
        BAR; LGKM0;
        MM(0, 0)
        BAR;
        // phase 1: quadrant (0,1)
        LDB(1)
        if (t < 15) STAGE(t + 1, 3)
        BAR; LGKM0;
        MM(0, 1)
        BAR;
        // phase 2: quadrant (1,1)
        LDA(1)
        BAR; LGKM0;
        MM(1, 1)
        BAR;
        // phase 3: quadrant (1,0); A-region of current buf is dead -> prefetch t+2
        LDB(0)
        if (t < 14) { STAGE(t + 2, 0) STAGE(t + 2, 1) }
        BAR; LGKM0;
        MM(1, 0)
        if (t < 14)       asm volatile("s_waitcnt vmcnt(4)" ::: "memory");
        else if (t == 14) asm volatile("s_waitcnt vmcnt(0)" ::: "memory");
        if (t < 15) BAR;
    }

#undef STAGE_HALF
#undef STAGE
#undef LDA
#undef LDB
#undef MM
#undef LGKM0
#undef BAR

    #pragma unroll
    for (int mf = 0; mf < 8; ++mf)
        #pragma unroll
        for (int nf = 0; nf < 4; ++nf)
            #pragma unroll
            for (int rr = 0; rr < 4; ++rr) {
                int row = m0 + wm * 128 + mf * 16 + quad * 4 + rr;
                int col = n0 + wn * 64 + nf * 16 + ln;
                Y[(size_t)row * D_ + col] = f2bf(acc[mf][nf][rr] * scale);
            }
}

// ---------------------------------------------------------------------------
// vt_trans: V[b][s][e] -> Vt[b][e][s]
// ---------------------------------------------------------------------------
__global__ __launch_bounds__(256) void vt_trans(const unsigned short* __restrict__ V,
                                                unsigned short* __restrict__ Vt) {
    __shared__ unsigned short ls[64 * 66];
    const int s0 = blockIdx.x * 64, e0 = blockIdx.y * 64, b = blockIdx.z;
    const int tid = threadIdx.x;
    const size_t base = (size_t)b * S_ * D_;
    #pragma unroll
    for (int i = 0; i < 16; ++i) {
        int lin = i * 256 + tid, r = lin >> 6, c = lin & 63;
        ls[r * 66 + c] = V[base + (size_t)(s0 + r) * D_ + e0 + c];
    }
    __syncthreads();
    const size_t baseT = (size_t)b * D_ * S_;
    #pragma unroll
    for (int i = 0; i < 16; ++i) {
        int lin = i * 256 + tid, r = lin >> 6, c = lin & 63;
        Vt[baseT + (size_t)(e0 + r) * S_ + s0 + c] = ls[c * 66 + r];
    }
}

// ---------------------------------------------------------------------------
// qk_pexp: per lower-tri tile pair: P = exp(Q@K^T) bf16 tile-packed, partial l.
// XCD-swizzled: XCD r owns qt rows {r, 31-r, 8+r, 23-r} (66 blocks each).
// ---------------------------------------------------------------------------
__global__ __launch_bounds__(256) void qk_pexp(
    const unsigned short* __restrict__ Q, const unsigned short* __restrict__ K,
    unsigned short* __restrict__ P, float* __restrict__ lpart)
{
    __shared__ __align__(16) unsigned short lsA[4096];
    __shared__ __align__(16) unsigned short lsB[4096];
    __shared__ float sml[2][128];

    const int l = blockIdx.x, b = blockIdx.y;
    const int r = l & 7;          // xcd
    const int s = l >> 3;         // 0..65
    int qt, kt;
    if (s < r + 1)            { qt = r;      kt = s; }
    else if (s < 33)          { qt = 31 - r; kt = s - (r + 1); }
    else if (s < 42 + r)      { qt = 8 + r;  kt = s - 33; }
    else                      { qt = 23 - r; kt = s - (42 + r); }
    const int p = qt * (qt + 1) / 2 + kt;

    const int q0 = qt * 128, k0 = kt * 128;
    const int tid = threadIdx.x, lane = tid & 63, w = tid >> 6;
    const int wm = w >> 1, wn = w & 1, quad = lane >> 4, ln = lane & 15;
    const size_t base = (size_t)b * S_ * D_;

    const unsigned short* Qb = Q + base + (size_t)q0 * D_;
    const unsigned short* Kb = K + base + (size_t)k0 * D_;

    f32x4 acc[4][4] = {};
    for (int et = 0; et < D_ / 32; ++et) {
        stage128x32(Qb + et * 32, D_, lsA, tid);
        stage128x32(Kb + et * 32, D_, lsB, tid);
        __syncthreads();
        short8 af[4], bfr[4];
        #pragma unroll
        for (int mf = 0; mf < 4; ++mf)
            af[mf] = *(const short8*)&lsA[(wm * 64 + mf * 16 + ln) * 32 + quad * 8];
        #pragma unroll
        for (int nf = 0; nf < 4; ++nf)
            bfr[nf] = *(const short8*)&lsB[(wn * 64 + nf * 16 + ln) * 32 + quad * 8];
        #pragma unroll
        for (int mf = 0; mf < 4; ++mf)
            #pragma unroll
            for (int nf = 0; nf < 4; ++nf)
                acc[mf][nf] = __builtin_amdgcn_mfma_f32_16x16x32_bf16(af[mf], bfr[nf], acc[mf][nf], 0, 0, 0);
        __syncthreads();
    }

    const bool diag = (kt == qt);
    unsigned short* Pt = P + ((size_t)b * PAIRS_ + p) * (128 * 128);

    #pragma unroll
    for (int mf = 0; mf < 4; ++mf)
        #pragma unroll
        for (int rr = 0; rr < 4; ++rr) {
            int rowq = wm * 64 + mf * 16 + quad * 4 + rr;
            float lsum = 0.0f;
            #pragma unroll
            for (int nf = 0; nf < 4; ++nf) {
                int ckey = wn * 64 + nf * 16 + ln;
                float sc = acc[mf][nf][rr];
                float pe = (diag && ckey > rowq) ? 0.0f : __expf(fminf(sc, 60.0f));
                Pt[rowq * 128 + ckey] = f2bf(pe);
                lsum += pe;
            }
            #pragma unroll
            for (int off = 1; off < 16; off <<= 1)
                lsum += __shfl_xor(lsum, off);
            if (ln == 0) sml[wn][rowq] = lsum;
        }
    __syncthreads();

    if (tid < 128)
        lpart[((size_t)b * PAIRS_ + p) * 128 + tid] = sml[0][tid] + sml[1][tid];
}

// ---------------------------------------------------------------------------
// merge_il: il[b][q] = 1 / sum_kt l_t
// ---------------------------------------------------------------------------
__global__ __launch_bounds__(128) void merge_il(const float* __restrict__ lpart,
                                                float* __restrict__ il) {
    const int qt = blockIdx.x, b = blockIdx.y;
    const int row = threadIdx.x;
    const int pbase = qt * (qt + 1) / 2;
    float l = 0.0f;
    for (int kt = 0; kt <= qt; ++kt)
        l += lpart[((size_t)b * PAIRS_ + pbase + kt) * 128 + row];
    il[(size_t)b * S_ + qt * 128 + row] = 1.0f / l;
}

// ---------------------------------------------------------------------------
// pv_gemm: O = (P @ V) * il. 128x128 tiles, PAIRED q-tiles for exact balance:
// each block does qt = 31-pair (heavy) then qt = pair; combined K-extent is
// always 33 ktiles -> every one of the 512 blocks does identical work
// (2 blocks/CU, 66 units/CU, zero tail). dt = lin&7 keeps Vt slice XCD-local.
// ---------------------------------------------------------------------------
__global__ __launch_bounds__(256) void pv_gemm(
    const unsigned short* __restrict__ P, const unsigned short* __restrict__ Vt,
    const float* __restrict__ il, float* __restrict__ O)
{
    __shared__ __align__(16) unsigned short lsA[4096];
    __shared__ __align__(16) unsigned short lsB[4096];

    const int l = blockIdx.x;            // 0..511
    const int dt = l & 7;                // xcd-local d-slice
    const int s = l >> 3;                // 0..63
    const int pair = s & 15;
    const int b = s >> 4;
    const int d0 = dt * 128;
    const int tid = threadIdx.x, lane = tid & 63, w = tid >> 6;
    const int wm = w >> 1, wn = w & 1, quad = lane >> 4, ln = lane & 15;

    const unsigned short* Vtb = Vt + ((size_t)b * D_ + d0) * S_;

    #pragma unroll 1
    for (int half = 0; half < 2; ++half) {
        const int qt = half ? pair : (31 - pair);   // heavy first
        const int q0 = qt * 128;
        const int pbase = qt * (qt + 1) / 2;

        f32x4 acc[4][4] = {};

        #pragma unroll 1
        for (int ktile = 0; ktile <= qt; ++ktile) {
            const unsigned short* Ptile = P + ((size_t)b * PAIRS_ + pbase + ktile) * (128 * 128);
            #pragma unroll 1
            for (int sub = 0; sub < 4; ++sub) {
                stage128x32(Ptile + sub * 32, 128, lsA, tid);
                stage128x32(Vtb + ktile * 128 + sub * 32, S_, lsB, tid);
                __syncthreads();
                short8 af[4], bfr[4];
                #pragma unroll
                for (int mf = 0; mf < 4; ++mf)
                    af[mf] = *(const short8*)&lsA[(wm * 64 + mf * 16 + ln) * 32 + quad * 8];
                #pragma unroll
                for (int nf = 0; nf < 4; ++nf)
                    bfr[nf] = *(const short8*)&lsB[(wn * 64 + nf * 16 + ln) * 32 + quad * 8];
                #pragma unroll
                for (int mf = 0; mf < 4; ++mf)
                    #pragma unroll
                    for (int nf = 0; nf < 4; ++nf)
                        acc[mf][nf] = __builtin_amdgcn_mfma_f32_16x16x32_bf16(af[mf], bfr[nf], acc[mf][nf], 0, 0, 0);
                __syncthreads();
            }
        }

        #pragma unroll
        for (int mf = 0; mf < 4; ++mf) {
            float ilv[4];
            #pragma unroll
            for (int rr = 0; rr < 4; ++rr)
                ilv[rr] = il[(size_t)b * S_ + q0 + wm * 64 + mf * 16 + quad * 4 + rr];
            #pragma unroll
            for (int nf = 0; nf < 2; ++nf)
                #pragma unroll
                for (int rr = 0; rr < 4; ++rr) {
                    int rowq = q0 + wm * 64 + mf * 16 + quad * 4 + rr;
                    int col = d0 + wn * 64 + nf * 16 + ln;
                    O[((size_t)b * S_ + rowq) * D_ + col] = acc[mf][nf][rr] * ilv[rr];
                }
            #pragma unroll
            for (int nf = 2; nf < 4; ++nf)
                #pragma unroll
                for (int rr = 0; rr < 4; ++rr) {
                    int rowq = q0 + wm * 64 + mf * 16 + quad * 4 + rr;
                    int col = d0 + wn * 64 + nf * 16 + ln;
                    O[((size_t)b * S_ + rowq) * D_ + col] = acc[mf][nf][rr] * ilv[rr];
                }
        }
    }
}

extern "C" void kernel_launch(void* const* d_in, const int* in_sizes, int n_in,
                              void* d_out, int out_size, void* d_ws, size_t ws_size,
                              hipStream_t stream) {
    const float* x  = (const float*)d_in[0];
    const float* Wq = (const float*)d_in[1];
    const float* Wk = (const float*)d_in[2];
    const float* Wv = (const float*)d_in[3];

    const size_t nQ = (size_t)B_ * S_ * D_;
    const size_t nP = (size_t)B_ * PAIRS_ * 128 * 128;

    unsigned short* P  = (unsigned short*)d_ws;
    unsigned short* V  = P;                       // alias: dead before P written
    unsigned short* Q  = P + nP;
    unsigned short* K  = Q + nQ;
    unsigned short* Vt = K + nQ;
    unsigned short* xb = Vt;                      // alias: dead before Vt written
    unsigned short* Wt = Vt + nQ;
    float* lpart = (float*)(Wt + (size_t)3 * D_ * D_);
    float* il    = lpart + (size_t)B_ * PAIRS_ * 128;
    float* O = (float*)d_out;

    hipLaunchKernelGGL(prep_x, dim3(8192), dim3(256), 0, stream, x, xb);
    hipLaunchKernelGGL(prep_w, dim3(16, 16, 3), dim3(256), 0, stream, Wq, Wk, Wv, Wt);
    hipLaunchKernelGGL(qkv_gemm, dim3(256, 1, 3), dim3(512), 0, stream, xb, Wt, Q, K, V);
    hipLaunchKernelGGL(vt_trans, dim3(64, 16, B_), dim3(256), 0, stream, V, Vt);
    hipLaunchKernelGGL(qk_pexp, dim3(PAIRS_, B_), dim3(256), 0, stream, Q, K, P, lpart);
    hipLaunchKernelGGL(merge_il, dim3(NT_, B_), dim3(128), 0, stream, lpart, il);
    hipLaunchKernelGGL(pv_gemm, dim3(512), dim3(256), 0, stream, P, Vt, il, O);
}

// Round 2
// 442.107 us; speedup vs baseline: 1.0357x; 1.0357x over previous
//
#include <hip/hip_runtime.h>
#include <hip/hip_bf16.h>

#define B_ 4
#define S_ 4096
#define D_ 1024
#define NT_ 32        // S_/128
#define PAIRS_ 528    // NT_*(NT_+1)/2 lower-triangle tile pairs

typedef __attribute__((ext_vector_type(8))) short short8;
typedef __attribute__((ext_vector_type(4))) float f32x4;

__device__ __forceinline__ unsigned short f2bf(float f) {
    union { float f; unsigned u; } v; v.f = f;
    unsigned u = v.u;
    return (unsigned short)((u + 0x7fffu + ((u >> 16) & 1u)) >> 16);
}

// async global->LDS, 16B per lane. LDS dst is wave-uniform base + lane*16.
__device__ __forceinline__ void gld_lds16(const unsigned short* g, unsigned short* l) {
    __builtin_amdgcn_global_load_lds((const __attribute__((address_space(1))) void*)g,
                                     (__attribute__((address_space(3))) void*)l, 16, 0, 0);
}

// stage a 128x32 bf16 tile (global row stride = ld elems) into contiguous LDS [128][32]
__device__ __forceinline__ void stage128x32(const unsigned short* gbase, size_t ld,
                                            unsigned short* ls, int tid) {
    const int r = tid >> 2;
    const int c = (tid & 3) * 8;
    unsigned short* lw = ls + tid * 8;
    gld_lds16(gbase + (size_t)r * ld + c, lw);
    gld_lds16(gbase + (size_t)(r + 64) * ld + c, lw + 2048);
}

// ---------------------------------------------------------------------------
// prep_x: fp32 x -> bf16 xb
// ---------------------------------------------------------------------------
__global__ __launch_bounds__(256) void prep_x(const float* __restrict__ x,
                                              unsigned short* __restrict__ xb) {
    size_t i = ((size_t)blockIdx.x * 256 + threadIdx.x) * 8;
    float4 a = *(const float4*)&x[i];
    float4 b = *(const float4*)&x[i + 4];
    unsigned u0 = (unsigned)f2bf(a.x) | ((unsigned)f2bf(a.y) << 16);
    unsigned u1 = (unsigned)f2bf(a.z) | ((unsigned)f2bf(a.w) << 16);
    unsigned u2 = (unsigned)f2bf(b.x) | ((unsigned)f2bf(b.y) << 16);
    unsigned u3 = (unsigned)f2bf(b.z) | ((unsigned)f2bf(b.w) << 16);
    uint4 val; val.x = u0; val.y = u1; val.z = u2; val.w = u3;
    *(uint4*)&xb[i] = val;
}

// ---------------------------------------------------------------------------
// prep_w: W[k][n] fp32 -> Wt[n][k] bf16
// ---------------------------------------------------------------------------
__global__ __launch_bounds__(256) void prep_w(const float* __restrict__ Wq,
                                              const float* __restrict__ Wk,
                                              const float* __restrict__ Wv,
                                              unsigned short* __restrict__ Wt) {
    __shared__ float ls[64 * 65];
    const int z = blockIdx.z;
    const float* __restrict__ W = (z == 0) ? Wq : (z == 1) ? Wk : Wv;
    unsigned short* __restrict__ Wtz = Wt + (size_t)z * D_ * D_;
    const int k0 = blockIdx.y * 64, n0 = blockIdx.x * 64;
    const int tid = threadIdx.x;
    #pragma unroll
    for (int i = 0; i < 16; ++i) {
        int lin = i * 256 + tid, r = lin >> 6, c = lin & 63;
        ls[r * 65 + c] = W[(size_t)(k0 + r) * D_ + n0 + c];
    }
    __syncthreads();
    #pragma unroll
    for (int i = 0; i < 16; ++i) {
        int lin = i * 256 + tid, r = lin >> 6, c = lin & 63;
        Wtz[(size_t)(n0 + r) * D_ + k0 + c] = f2bf(ls[c * 65 + r]);
    }
}

// ---------------------------------------------------------------------------
// qkv_gemm: Y = xb @ Wt_z^T.
// 256x256 tile, BK=64, 8 waves (2Mx4N), st-swizzled LDS (T2 via inverse-
// swizzled global source + swizzled ds_read), setprio around MFMA (T5).
// SINGLE barrier per K-tile: all t+1 half-tiles staged at TOP of tile t
// (issue-early, T14) into buf^1; reads+MFMAs free-ordered so the compiler
// emits fine-grained lgkmcnt(N) and the 2 waves/SIMD de-synchronize (one
// wave's MFMA overlaps the other's LDS drain). Boundary: per-wave
// lgkmcnt(0) (buf fully read -> next tile's A/B stage into it is safe),
// vmcnt(0) (residual ~0: loads had the whole tile to land, mostly L2),
// s_barrier. sched_barrier(0) pins the asm waits (rule #18).
// ---------------------------------------------------------------------------
__global__ __launch_bounds__(512, 2) void qkv_gemm(
    const unsigned short* __restrict__ xb, const unsigned short* __restrict__ Wt,
    unsigned short* __restrict__ Q, unsigned short* __restrict__ K,
    unsigned short* __restrict__ V)
{
    __shared__ __align__(16) unsigned short lsA[2 * 256 * 64];   // 64 KiB
    __shared__ __align__(16) unsigned short lsB[2 * 256 * 64];   // 64 KiB

    const int z = blockIdx.z;
    unsigned short* __restrict__ Y = (z == 0) ? Q : (z == 1) ? K : V;
    const float scale = (z == 0) ? 0.03125f : 1.0f;

    // XCD-aware swizzle: 256 wgs, 8 XCDs, 32 contiguous wgs per XCD, n-inner.
    const int lin = blockIdx.x;                       // 0..255
    const int wg = (lin & 7) * 32 + (lin >> 3);
    const int m0 = (wg >> 2) * 256, n0 = (wg & 3) * 256;

    const int tid = threadIdx.x, lane = tid & 63, w = tid >> 6;
    const int wm = w >> 2, wn = w & 3;                // 2 x 4 wave grid
    const int quad = lane >> 4, ln = lane & 15;

    const unsigned short* Ab = xb + (size_t)m0 * D_;
    const unsigned short* Bb = Wt + (size_t)z * D_ * D_ + (size_t)n0 * D_;

    // Stage one 128x64 half-tile. Dest is LINEAR (global_load_lds constraint);
    // the XOR-16B-granule swizzle is applied on the SOURCE column so that the
    // swizzled ds_read below finds (row r, col-granule cg) at
    // byte (r*128) ^ (((cg^(r&7)))*16).  granule g: row=g>>3, src colg=(g&7)^(row&7).
#define STAGE_HALF(gbase, ldsbase)                                              \
    {                                                                           \
        _Pragma("unroll")                                                       \
        for (int i_ = 0; i_ < 2; ++i_) {                                        \
            int g_ = tid + i_ * 512;                                            \
            int r_ = g_ >> 3;                                                   \
            int cg_ = (g_ & 7) ^ (r_ & 7);                                      \
            gld_lds16((gbase) + (size_t)r_ * D_ + cg_ * 8, (ldsbase) + g_ * 8); \
        }                                                                       \
    }
    // half h: 0=A rows0..127, 1=A rows128..255, 2=B rows0..127, 3=B rows128..255
#define STAGE(kt, h)                                                                   \
    {                                                                                  \
        if ((h) < 2) { STAGE_HALF(Ab + (size_t)((h) * 128) * D_ + (kt) * 64,           \
                                  &lsA[(((kt) & 1) * 2 + (h)) * 8192]) }               \
        else         { STAGE_HALF(Bb + (size_t)(((h) - 2) * 128) * D_ + (kt) * 64,     \
                                  &lsB[(((kt) & 1) * 2 + ((h) - 2)) * 8192]) }         \
    }

    const unsigned short* As;
    const unsigned short* Bs;
    short8 a[4][2], b[2][2];
    f32x4 acc[8][4] = {};

#define LDA(mh)                                                                        \
    {                                                                                  \
        _Pragma("unroll")                                                              \
        for (int mf_ = 0; mf_ < 4; ++mf_) {                                            \
            _Pragma("unroll")                                                          \
            for (int ks_ = 0; ks_ < 2; ++ks_) {                                        \
                int r_ = wm * 128 + ((mh) * 4 + mf_) * 16 + ln;                        \
                int cg_ = ks_ * 4 + quad;                                              \
                a[mf_][ks_] = *(const short8*)&As[r_ * 64 + ((cg_ ^ (r_ & 7)) << 3)];  \
            }                                                                          \
        }                                                                              \
    }
#define LDB(nh)                                                                        \
    {                                                                                  \
        _Pragma("unroll")                                                              \
        for (int nf_ = 0; nf_ < 2; ++nf_) {                                            \
            _Pragma("unroll")                                                          \
            for (int ks_ = 0; ks_ < 2; ++ks_) {                                        \
                int r_ = wn * 64 + ((nh) * 2 + nf_) * 16 + ln;                         \
                int cg_ = ks_ * 4 + quad;                                              \
                b[nf_][ks_] = *(const short8*)&Bs[r_ * 64 + ((cg_ ^ (r_ & 7)) << 3)];  \
            }                                                                          \
        }                                                                              \
    }
#define MM(mh, nh)                                                                     \
    {                                                                                  \
        __builtin_amdgcn_s_setprio(1);                                                 \
        _Pragma("unroll")                                                              \
        for (int mf_ = 0; mf_ < 4; ++mf_)                                              \
            _Pragma("unroll")                                                          \
            for (int nf_ = 0; nf_ < 2; ++nf_)                                          \
                _Pragma("unroll")                                                      \
                for (int ks_ = 0; ks_ < 2; ++ks_)                                      \
                    acc[(mh) * 4 + mf_][(nh) * 2 + nf_] =                              \
                        __builtin_amdgcn_mfma_f32_16x16x32_bf16(                       \
                            a[mf_][ks_], b[nf_][ks_],                                  \
                            acc[(mh) * 4 + mf_][(nh) * 2 + nf_], 0, 0, 0);             \
        __builtin_amdgcn_s_setprio(0);                                                 \
    }
#define LGKM0 asm volatile("s_waitcnt lgkmcnt(0)" ::: "memory")
#define VM0   asm volatile("s_waitcnt vmcnt(0)" ::: "memory")
#define BAR   __builtin_amdgcn_s_barrier()
#define SB0   __builtin_amdgcn_sched_barrier(0)

    // prologue: stage full K-tile 0, drain, sync
    STAGE(0, 0) STAGE(0, 1) STAGE(0, 2) STAGE(0, 3)
    VM0; SB0;
    BAR; SB0;

    #pragma unroll 2
    for (int t = 0; t < 16; ++t) {
        As = lsA + (t & 1) * 16384;
        Bs = lsB + (t & 1) * 16384;
        // issue ALL of tile t+1's staging up front -> full tile to cover latency
        if (t < 15) { STAGE(t + 1, 0) STAGE(t + 1, 1) STAGE(t + 1, 2) STAGE(t + 1, 3) }
        SB0;
        // reads + MFMAs: no hard waits; compiler emits fine-grained lgkmcnt(N)
        LDA(0) LDB(0)
        MM(0, 0)
        LDB(1)
        MM(0, 1)
        LDA(1)
        MM(1, 1)
        LDB(0)
        MM(1, 0)
        // boundary: own reads drained (anti-dep for next tile's stage into buf),
        // own staged loads landed, then one barrier.
        LGKM0; SB0;
        if (t < 15) {
            VM0; SB0;
            BAR; SB0;
        }
    }

#undef STAGE_HALF
#undef STAGE
#undef LDA
#undef LDB
#undef MM
#undef LGKM0
#undef VM0
#undef BAR
#undef SB0

    #pragma unroll
    for (int mf = 0; mf < 8; ++mf)
        #pragma unroll
        for (int nf = 0; nf < 4; ++nf)
            #pragma unroll
            for (int rr = 0; rr < 4; ++rr) {
                int row = m0 + wm * 128 + mf * 16 + quad * 4 + rr;
                int col = n0 + wn * 64 + nf * 16 + ln;
                Y[(size_t)row * D_ + col] = f2bf(acc[mf][nf][rr] * scale);
            }
}

// ---------------------------------------------------------------------------
// vt_trans: V[b][s][e] -> Vt[b][e][s]
// ---------------------------------------------------------------------------
__global__ __launch_bounds__(256) void vt_trans(const unsigned short* __restrict__ V,
                                                unsigned short* __restrict__ Vt) {
    __shared__ unsigned short ls[64 * 66];
    const int s0 = blockIdx.x * 64, e0 = blockIdx.y * 64, b = blockIdx.z;
    const int tid = threadIdx.x;
    const size_t base = (size_t)b * S_ * D_;
    #pragma unroll
    for (int i = 0; i < 16; ++i) {
        int lin = i * 256 + tid, r = lin >> 6, c = lin & 63;
        ls[r * 66 + c] = V[base + (size_t)(s0 + r) * D_ + e0 + c];
    }
    __syncthreads();
    const size_t baseT = (size_t)b * D_ * S_;
    #pragma unroll
    for (int i = 0; i < 16; ++i) {
        int lin = i * 256 + tid, r = lin >> 6, c = lin & 63;
        Vt[baseT + (size_t)(e0 + r) * S_ + s0 + c] = ls[c * 66 + r];
    }
}

// ---------------------------------------------------------------------------
// qk_pexp: per lower-tri tile pair: P = exp(Q@K^T) bf16 tile-packed, partial l.
// XCD-swizzled: XCD r owns qt rows {r, 31-r, 8+r, 23-r} (66 blocks each).
// ---------------------------------------------------------------------------
__global__ __launch_bounds__(256) void qk_pexp(
    const unsigned short* __restrict__ Q, const unsigned short* __restrict__ K,
    unsigned short* __restrict__ P, float* __restrict__ lpart)
{
    __shared__ __align__(16) unsigned short lsA[4096];
    __shared__ __align__(16) unsigned short lsB[4096];
    __shared__ float sml[2][128];

    const int l = blockIdx.x, b = blockIdx.y;
    const int r = l & 7;          // xcd
    const int s = l >> 3;         // 0..65
    int qt, kt;
    if (s < r + 1)            { qt = r;      kt = s; }
    else if (s < 33)          { qt = 31 - r; kt = s - (r + 1); }
    else if (s < 42 + r)      { qt = 8 + r;  kt = s - 33; }
    else                      { qt = 23 - r; kt = s - (42 + r); }
    const int p = qt * (qt + 1) / 2 + kt;

    const int q0 = qt * 128, k0 = kt * 128;
    const int tid = threadIdx.x, lane = tid & 63, w = tid >> 6;
    const int wm = w >> 1, wn = w & 1, quad = lane >> 4, ln = lane & 15;
    const size_t base = (size_t)b * S_ * D_;

    const unsigned short* Qb = Q + base + (size_t)q0 * D_;
    const unsigned short* Kb = K + base + (size_t)k0 * D_;

    f32x4 acc[4][4] = {};
    for (int et = 0; et < D_ / 32; ++et) {
        stage128x32(Qb + et * 32, D_, lsA, tid);
        stage128x32(Kb + et * 32, D_, lsB, tid);
        __syncthreads();
        short8 af[4], bfr[4];
        #pragma unroll
        for (int mf = 0; mf < 4; ++mf)
            af[mf] = *(const short8*)&lsA[(wm * 64 + mf * 16 + ln) * 32 + quad * 8];
        #pragma unroll
        for (int nf = 0; nf < 4; ++nf)
            bfr[nf] = *(const short8*)&lsB[(wn * 64 + nf * 16 + ln) * 32 + quad * 8];
        #pragma unroll
        for (int mf = 0; mf < 4; ++mf)
            #pragma unroll
            for (int nf = 0; nf < 4; ++nf)
                acc[mf][nf] = __builtin_amdgcn_mfma_f32_16x16x32_bf16(af[mf], bfr[nf], acc[mf][nf], 0, 0, 0);
        __syncthreads();
    }

    const bool diag = (kt == qt);
    unsigned short* Pt = P + ((size_t)b * PAIRS_ + p) * (128 * 128);

    #pragma unroll
    for (int mf = 0; mf < 4; ++mf)
        #pragma unroll
        for (int rr = 0; rr < 4; ++rr) {
            int rowq = wm * 64 + mf * 16 + quad * 4 + rr;
            float lsum = 0.0f;
            #pragma unroll
            for (int nf = 0; nf < 4; ++nf) {
                int ckey = wn * 64 + nf * 16 + ln;
                float sc = acc[mf][nf][rr];
                float pe = (diag && ckey > rowq) ? 0.0f : __expf(fminf(sc, 60.0f));
                Pt[rowq * 128 + ckey] = f2bf(pe);
                lsum += pe;
            }
            #pragma unroll
            for (int off = 1; off < 16; off <<= 1)
                lsum += __shfl_xor(lsum, off);
            if (ln == 0) sml[wn][rowq] = lsum;
        }
    __syncthreads();

    if (tid < 128)
        lpart[((size_t)b * PAIRS_ + p) * 128 + tid] = sml[0][tid] + sml[1][tid];
}

// ---------------------------------------------------------------------------
// merge_il: il[b][q] = 1 / sum_kt l_t
// ---------------------------------------------------------------------------
__global__ __launch_bounds__(128) void merge_il(const float* __restrict__ lpart,
                                                float* __restrict__ il) {
    const int qt = blockIdx.x, b = blockIdx.y;
    const int row = threadIdx.x;
    const int pbase = qt * (qt + 1) / 2;
    float l = 0.0f;
    for (int kt = 0; kt <= qt; ++kt)
        l += lpart[((size_t)b * PAIRS_ + pbase + kt) * 128 + row];
    il[(size_t)b * S_ + qt * 128 + row] = 1.0f / l;
}

// ---------------------------------------------------------------------------
// pv_gemm: O = (P @ V) * il. 128x128 tiles, PAIRED q-tiles for exact balance:
// each block does qt = 31-pair (heavy) then qt = pair; combined K-extent is
// always 33 ktiles -> every one of the 512 blocks does identical work
// (2 blocks/CU, 66 units/CU, zero tail). dt = lin&7 keeps Vt slice XCD-local.
// ---------------------------------------------------------------------------
__global__ __launch_bounds__(256) void pv_gemm(
    const unsigned short* __restrict__ P, const unsigned short* __restrict__ Vt,
    const float* __restrict__ il, float* __restrict__ O)
{
    __shared__ __align__(16) unsigned short lsA[4096];
    __shared__ __align__(16) unsigned short lsB[4096];

    const int l = blockIdx.x;            // 0..511
    const int dt = l & 7;                // xcd-local d-slice
    const int s = l >> 3;                // 0..63
    const int pair = s & 15;
    const int b = s >> 4;
    const int d0 = dt * 128;
    const int tid = threadIdx.x, lane = tid & 63, w = tid >> 6;
    const int wm = w >> 1, wn = w & 1, quad = lane >> 4, ln = lane & 15;

    const unsigned short* Vtb = Vt + ((size_t)b * D_ + d0) * S_;

    #pragma unroll 1
    for (int half = 0; half < 2; ++half) {
        const int qt = half ? pair : (31 - pair);   // heavy first
        const int q0 = qt * 128;
        const int pbase = qt * (qt + 1) / 2;

        f32x4 acc[4][4] = {};

        #pragma unroll 1
        for (int ktile = 0; ktile <= qt; ++ktile) {
            const unsigned short* Ptile = P + ((size_t)b * PAIRS_ + pbase + ktile) * (128 * 128);
            #pragma unroll 1
            for (int sub = 0; sub < 4; ++sub) {
                stage128x32(Ptile + sub * 32, 128, lsA, tid);
                stage128x32(Vtb + ktile * 128 + sub * 32, S_, lsB, tid);
                __syncthreads();
                short8 af[4], bfr[4];
                #pragma unroll
                for (int mf = 0; mf < 4; ++mf)
                    af[mf] = *(const short8*)&lsA[(wm * 64 + mf * 16 + ln) * 32 + quad * 8];
                #pragma unroll
                for (int nf = 0; nf < 4; ++nf)
                    bfr[nf] = *(const short8*)&lsB[(wn * 64 + nf * 16 + ln) * 32 + quad * 8];
                #pragma unroll
                for (int mf = 0; mf < 4; ++mf)
                    #pragma unroll
                    for (int nf = 0; nf < 4; ++nf)
                        acc[mf][nf] = __builtin_amdgcn_mfma_f32_16x16x32_bf16(af[mf], bfr[nf], acc[mf][nf], 0, 0, 0);
                __syncthreads();
            }
        }

        #pragma unroll
        for (int mf = 0; mf < 4; ++mf) {
            float ilv[4];
            #pragma unroll
            for (int rr = 0; rr < 4; ++rr)
                ilv[rr] = il[(size_t)b * S_ + q0 + wm * 64 + mf * 16 + quad * 4 + rr];
            #pragma unroll
            for (int nf = 0; nf < 4; ++nf)
                #pragma unroll
                for (int rr = 0; rr < 4; ++rr) {
                    int rowq = q0 + wm * 64 + mf * 16 + quad * 4 + rr;
                    int col = d0 + wn * 64 + nf * 16 + ln;
                    O[((size_t)b * S_ + rowq) * D_ + col] = acc[mf][nf][rr] * ilv[rr];
                }
        }
    }
}

extern "C" void kernel_launch(void* const* d_in, const int* in_sizes, int n_in,
                              void* d_out, int out_size, void* d_ws, size_t ws_size,
                              hipStream_t stream) {
    const float* x  = (const float*)d_in[0];
    const float* Wq = (const float*)d_in[1];
    const float* Wk = (const float*)d_in[2];
    const float* Wv = (const float*)d_in[3];

    const size_t nQ = (size_t)B_ * S_ * D_;
    const size_t nP = (size_t)B_ * PAIRS_ * 128 * 128;

    unsigned short* P  = (unsigned short*)d_ws;
    unsigned short* V  = P;                       // alias: dead before P written
    unsigned short* Q  = P + nP;
    unsigned short* K  = Q + nQ;
    unsigned short* Vt = K + nQ;
    unsigned short* xb = Vt;                      // alias: dead before Vt written
    unsigned short* Wt = Vt + nQ;
    float* lpart = (float*)(Wt + (size_t)3 * D_ * D_);
    float* il    = lpart + (size_t)B_ * PAIRS_ * 128;
    float* O = (float*)d_out;

    hipLaunchKernelGGL(prep_x, dim3(8192), dim3(256), 0, stream, x, xb);
    hipLaunchKernelGGL(prep_w, dim3(16, 16, 3), dim3(256), 0, stream, Wq, Wk, Wv, Wt);
    hipLaunchKernelGGL(qkv_gemm, dim3(256, 1, 3), dim3(512), 0, stream, xb, Wt, Q, K, V);
    hipLaunchKernelGGL(vt_trans, dim3(64, 16, B_), dim3(256), 0, stream, V, Vt);
    hipLaunchKernelGGL(qk_pexp, dim3(PAIRS_, B_), dim3(256), 0, stream, Q, K, P, lpart);
    hipLaunchKernelGGL(merge_il, dim3(NT_, B_), dim3(128), 0, stream, lpart, il);
    hipLaunchKernelGGL(pv_gemm, dim3(512), dim3(256), 0, stream, P, Vt, il, O);
}

// Round 3
// 429.792 us; speedup vs baseline: 1.0654x; 1.0287x over previous
//
#include <hip/hip_runtime.h>
#include <hip/hip_bf16.h>

#define B_ 4
#define S_ 4096
#define D_ 1024
#define NT_ 32        // S_/128
#define PAIRS_ 528    // NT_*(NT_+1)/2 lower-triangle tile pairs

typedef __attribute__((ext_vector_type(8))) short short8;
typedef __attribute__((ext_vector_type(4))) float f32x4;

__device__ __forceinline__ unsigned short f2bf(float f) {
    union { float f; unsigned u; } v; v.f = f;
    unsigned u = v.u;
    return (unsigned short)((u + 0x7fffu + ((u >> 16) & 1u)) >> 16);
}

// async global->LDS, 16B per lane. LDS dst is wave-uniform base + lane*16.
__device__ __forceinline__ void gld_lds16(const unsigned short* g, unsigned short* l) {
    __builtin_amdgcn_global_load_lds((const __attribute__((address_space(1))) void*)g,
                                     (__attribute__((address_space(3))) void*)l, 16, 0, 0);
}

#define LGKM0 asm volatile("s_waitcnt lgkmcnt(0)" ::: "memory")
#define VM0   asm volatile("s_waitcnt vmcnt(0)" ::: "memory")
#define BAR   __builtin_amdgcn_s_barrier()
#define SB0   __builtin_amdgcn_sched_barrier(0)

// ---------------------------------------------------------------------------
// prep_x: fp32 x -> bf16 xb
// ---------------------------------------------------------------------------
__global__ __launch_bounds__(256) void prep_x(const float* __restrict__ x,
                                              unsigned short* __restrict__ xb) {
    size_t i = ((size_t)blockIdx.x * 256 + threadIdx.x) * 8;
    float4 a = *(const float4*)&x[i];
    float4 b = *(const float4*)&x[i + 4];
    unsigned u0 = (unsigned)f2bf(a.x) | ((unsigned)f2bf(a.y) << 16);
    unsigned u1 = (unsigned)f2bf(a.z) | ((unsigned)f2bf(a.w) << 16);
    unsigned u2 = (unsigned)f2bf(b.x) | ((unsigned)f2bf(b.y) << 16);
    unsigned u3 = (unsigned)f2bf(b.z) | ((unsigned)f2bf(b.w) << 16);
    uint4 val; val.x = u0; val.y = u1; val.z = u2; val.w = u3;
    *(uint4*)&xb[i] = val;
}

// ---------------------------------------------------------------------------
// prep_w: W[k][n] fp32 -> Wt[n][k] bf16
// ---------------------------------------------------------------------------
__global__ __launch_bounds__(256) void prep_w(const float* __restrict__ Wq,
                                              const float* __restrict__ Wk,
                                              const float* __restrict__ Wv,
                                              unsigned short* __restrict__ Wt) {
    __shared__ float ls[64 * 65];
    const int z = blockIdx.z;
    const float* __restrict__ W = (z == 0) ? Wq : (z == 1) ? Wk : Wv;
    unsigned short* __restrict__ Wtz = Wt + (size_t)z * D_ * D_;
    const int k0 = blockIdx.y * 64, n0 = blockIdx.x * 64;
    const int tid = threadIdx.x;
    #pragma unroll
    for (int i = 0; i < 16; ++i) {
        int lin = i * 256 + tid, r = lin >> 6, c = lin & 63;
        ls[r * 65 + c] = W[(size_t)(k0 + r) * D_ + n0 + c];
    }
    __syncthreads();
    #pragma unroll
    for (int i = 0; i < 16; ++i) {
        int lin = i * 256 + tid, r = lin >> 6, c = lin & 63;
        Wtz[(size_t)(n0 + r) * D_ + k0 + c] = f2bf(ls[c * 65 + r]);
    }
}

// ---------------------------------------------------------------------------
// qkv_gemm: Y = xb @ Wt_z^T.  (unchanged from round 2: 256x256, BK=64,
// 8 waves, source-swizzled LDS, single barrier/K-tile, setprio)
// ---------------------------------------------------------------------------
__global__ __launch_bounds__(512, 2) void qkv_gemm(
    const unsigned short* __restrict__ xb, const unsigned short* __restrict__ Wt,
    unsigned short* __restrict__ Q, unsigned short* __restrict__ K,
    unsigned short* __restrict__ V)
{
    __shared__ __align__(16) unsigned short lsA[2 * 256 * 64];   // 64 KiB
    __shared__ __align__(16) unsigned short lsB[2 * 256 * 64];   // 64 KiB

    const int z = blockIdx.z;
    unsigned short* __restrict__ Y = (z == 0) ? Q : (z == 1) ? K : V;
    const float scale = (z == 0) ? 0.03125f : 1.0f;

    const int lin = blockIdx.x;                       // 0..255
    const int wg = (lin & 7) * 32 + (lin >> 3);
    const int m0 = (wg >> 2) * 256, n0 = (wg & 3) * 256;

    const int tid = threadIdx.x, lane = tid & 63, w = tid >> 6;
    const int wm = w >> 2, wn = w & 3;                // 2 x 4 wave grid
    const int quad = lane >> 4, ln = lane & 15;

    const unsigned short* Ab = xb + (size_t)m0 * D_;
    const unsigned short* Bb = Wt + (size_t)z * D_ * D_ + (size_t)n0 * D_;

#define STAGE_HALF(gbase, ldsbase)                                              \
    {                                                                           \
        _Pragma("unroll")                                                       \
        for (int i_ = 0; i_ < 2; ++i_) {                                        \
            int g_ = tid + i_ * 512;                                            \
            int r_ = g_ >> 3;                                                   \
            int cg_ = (g_ & 7) ^ (r_ & 7);                                      \
            gld_lds16((gbase) + (size_t)r_ * D_ + cg_ * 8, (ldsbase) + g_ * 8); \
        }                                                                       \
    }
#define STAGE(kt, h)                                                                   \
    {                                                                                  \
        if ((h) < 2) { STAGE_HALF(Ab + (size_t)((h) * 128) * D_ + (kt) * 64,           \
                                  &lsA[(((kt) & 1) * 2 + (h)) * 8192]) }               \
        else         { STAGE_HALF(Bb + (size_t)(((h) - 2) * 128) * D_ + (kt) * 64,     \
                                  &lsB[(((kt) & 1) * 2 + ((h) - 2)) * 8192]) }         \
    }

    const unsigned short* As;
    const unsigned short* Bs;
    short8 a[4][2], b[2][2];
    f32x4 acc[8][4] = {};

#define LDA(mh)                                                                        \
    {                                                                                  \
        _Pragma("unroll")                                                              \
        for (int mf_ = 0; mf_ < 4; ++mf_) {                                            \
            _Pragma("unroll")                                                          \
            for (int ks_ = 0; ks_ < 2; ++ks_) {                                        \
                int r_ = wm * 128 + ((mh) * 4 + mf_) * 16 + ln;                        \
                int cg_ = ks_ * 4 + quad;                                              \
                a[mf_][ks_] = *(const short8*)&As[r_ * 64 + ((cg_ ^ (r_ & 7)) << 3)];  \
            }                                                                          \
        }                                                                              \
    }
#define LDB(nh)                                                                        \
    {                                                                                  \
        _Pragma("unroll")                                                              \
        for (int nf_ = 0; nf_ < 2; ++nf_) {                                            \
            _Pragma("unroll")                                                          \
            for (int ks_ = 0; ks_ < 2; ++ks_) {                                        \
                int r_ = wn * 64 + ((nh) * 2 + nf_) * 16 + ln;                         \
                int cg_ = ks_ * 4 + quad;                                              \
                b[nf_][ks_] = *(const short8*)&Bs[r_ * 64 + ((cg_ ^ (r_ & 7)) << 3)];  \
            }                                                                          \
        }                                                                              \
    }
#define MM(mh, nh)                                                                     \
    {                                                                                  \
        __builtin_amdgcn_s_setprio(1);                                                 \
        _Pragma("unroll")                                                              \
        for (int mf_ = 0; mf_ < 4; ++mf_)                                              \
            _Pragma("unroll")                                                          \
            for (int nf_ = 0; nf_ < 2; ++nf_)                                          \
                _Pragma("unroll")                                                      \
                for (int ks_ = 0; ks_ < 2; ++ks_)                                      \
                    acc[(mh) * 4 + mf_][(nh) * 2 + nf_] =                              \
                        __builtin_amdgcn_mfma_f32_16x16x32_bf16(                       \
                            a[mf_][ks_], b[nf_][ks_],                                  \
                            acc[(mh) * 4 + mf_][(nh) * 2 + nf_], 0, 0, 0);             \
        __builtin_amdgcn_s_setprio(0);                                                 \
    }

    STAGE(0, 0) STAGE(0, 1) STAGE(0, 2) STAGE(0, 3)
    VM0; SB0;
    BAR; SB0;

    #pragma unroll 2
    for (int t = 0; t < 16; ++t) {
        As = lsA + (t & 1) * 16384;
        Bs = lsB + (t & 1) * 16384;
        if (t < 15) { STAGE(t + 1, 0) STAGE(t + 1, 1) STAGE(t + 1, 2) STAGE(t + 1, 3) }
        SB0;
        LDA(0) LDB(0)
        MM(0, 0)
        LDB(1)
        MM(0, 1)
        LDA(1)
        MM(1, 1)
        LDB(0)
        MM(1, 0)
        LGKM0; SB0;
        if (t < 15) {
            VM0; SB0;
            BAR; SB0;
        }
    }

#undef STAGE_HALF
#undef STAGE
#undef LDA
#undef LDB
#undef MM

    #pragma unroll
    for (int mf = 0; mf < 8; ++mf)
        #pragma unroll
        for (int nf = 0; nf < 4; ++nf)
            #pragma unroll
            for (int rr = 0; rr < 4; ++rr) {
                int row = m0 + wm * 128 + mf * 16 + quad * 4 + rr;
                int col = n0 + wn * 64 + nf * 16 + ln;
                Y[(size_t)row * D_ + col] = f2bf(acc[mf][nf][rr] * scale);
            }
}

// ---------------------------------------------------------------------------
// vt_trans: V[b][s][e] -> Vt[b][e][s]
// ---------------------------------------------------------------------------
__global__ __launch_bounds__(256) void vt_trans(const unsigned short* __restrict__ V,
                                                unsigned short* __restrict__ Vt) {
    __shared__ unsigned short ls[64 * 66];
    const int s0 = blockIdx.x * 64, e0 = blockIdx.y * 64, b = blockIdx.z;
    const int tid = threadIdx.x;
    const size_t base = (size_t)b * S_ * D_;
    #pragma unroll
    for (int i = 0; i < 16; ++i) {
        int lin = i * 256 + tid, r = lin >> 6, c = lin & 63;
        ls[r * 66 + c] = V[base + (size_t)(s0 + r) * D_ + e0 + c];
    }
    __syncthreads();
    const size_t baseT = (size_t)b * D_ * S_;
    #pragma unroll
    for (int i = 0; i < 16; ++i) {
        int lin = i * 256 + tid, r = lin >> 6, c = lin & 63;
        Vt[baseT + (size_t)(e0 + r) * S_ + s0 + c] = ls[c * 66 + r];
    }
}

// ---------------------------------------------------------------------------
// qk_pexp: per lower-tri tile pair: P = exp(Q@K^T) bf16 tile-packed, partial l.
// NEW: BK=64 double-buffered, source-swizzled staging + swizzled ds_read
// (bank-conflict-free), single barrier per K-tile, setprio around MFMA.
// 4 waves (2x2), 65 KB LDS -> 2 blocks/CU.
// XCD-swizzled: XCD r owns qt rows {r, 31-r, 8+r, 23-r} (66 blocks each).
// ---------------------------------------------------------------------------
__global__ __launch_bounds__(256, 2) void qk_pexp(
    const unsigned short* __restrict__ Q, const unsigned short* __restrict__ K,
    unsigned short* __restrict__ P, float* __restrict__ lpart)
{
    __shared__ __align__(16) unsigned short lsA[2 * 128 * 64];   // 32 KB
    __shared__ __align__(16) unsigned short lsB[2 * 128 * 64];   // 32 KB
    __shared__ float sml[2][128];

    const int l = blockIdx.x, b = blockIdx.y;
    const int r = l & 7;          // xcd
    const int s = l >> 3;         // 0..65
    int qt, kt;
    if (s < r + 1)            { qt = r;      kt = s; }
    else if (s < 33)          { qt = 31 - r; kt = s - (r + 1); }
    else if (s < 42 + r)      { qt = 8 + r;  kt = s - 33; }
    else                      { qt = 23 - r; kt = s - (42 + r); }
    const int p = qt * (qt + 1) / 2 + kt;

    const int q0 = qt * 128, k0 = kt * 128;
    const int tid = threadIdx.x, lane = tid & 63, w = tid >> 6;
    const int wm = w >> 1, wn = w & 1, quad = lane >> 4, ln = lane & 15;
    const size_t base = (size_t)b * S_ * D_;

    const unsigned short* Qb = Q + base + (size_t)q0 * D_;
    const unsigned short* Kb = K + base + (size_t)k0 * D_;

    // stage one 128x64 tile with inverse source swizzle (linear LDS dest)
#define QK_STAGE_HALF(gbase, ldsbase)                                           \
    {                                                                           \
        _Pragma("unroll")                                                       \
        for (int i_ = 0; i_ < 4; ++i_) {                                        \
            int g_ = tid + i_ * 256;                                            \
            int r_ = g_ >> 3;                                                   \
            int cg_ = (g_ & 7) ^ (r_ & 7);                                      \
            gld_lds16((gbase) + (size_t)r_ * D_ + cg_ * 8, (ldsbase) + g_ * 8); \
        }                                                                       \
    }
#define QK_STAGE(t)                                                             \
    {                                                                           \
        QK_STAGE_HALF(Qb + (t) * 64, &lsA[((t) & 1) * 8192])                    \
        QK_STAGE_HALF(Kb + (t) * 64, &lsB[((t) & 1) * 8192])                    \
    }

    short8 a[4][2], bfr[4][2];
    f32x4 acc[4][4] = {};

    QK_STAGE(0)
    VM0; SB0;
    BAR; SB0;

    #pragma unroll 2
    for (int t = 0; t < 16; ++t) {
        const unsigned short* As = lsA + (t & 1) * 8192;
        const unsigned short* Bs = lsB + (t & 1) * 8192;
        if (t < 15) QK_STAGE(t + 1)
        SB0;
        #pragma unroll
        for (int mf = 0; mf < 4; ++mf)
            #pragma unroll
            for (int ks = 0; ks < 2; ++ks) {
                int rr_ = wm * 64 + mf * 16 + ln;
                int cg_ = ks * 4 + quad;
                a[mf][ks] = *(const short8*)&As[rr_ * 64 + ((cg_ ^ (rr_ & 7)) << 3)];
            }
        #pragma unroll
        for (int nf = 0; nf < 4; ++nf)
            #pragma unroll
            for (int ks = 0; ks < 2; ++ks) {
                int rr_ = wn * 64 + nf * 16 + ln;
                int cg_ = ks * 4 + quad;
                bfr[nf][ks] = *(const short8*)&Bs[rr_ * 64 + ((cg_ ^ (rr_ & 7)) << 3)];
            }
        __builtin_amdgcn_s_setprio(1);
        #pragma unroll
        for (int mf = 0; mf < 4; ++mf)
            #pragma unroll
            for (int nf = 0; nf < 4; ++nf)
                #pragma unroll
                for (int ks = 0; ks < 2; ++ks)
                    acc[mf][nf] = __builtin_amdgcn_mfma_f32_16x16x32_bf16(
                        a[mf][ks], bfr[nf][ks], acc[mf][nf], 0, 0, 0);
        __builtin_amdgcn_s_setprio(0);
        LGKM0; SB0;
        if (t < 15) {
            VM0; SB0;
            BAR; SB0;
        }
    }
#undef QK_STAGE_HALF
#undef QK_STAGE

    const bool diag = (kt == qt);
    unsigned short* Pt = P + ((size_t)b * PAIRS_ + p) * (128 * 128);

    #pragma unroll
    for (int mf = 0; mf < 4; ++mf)
        #pragma unroll
        for (int rr = 0; rr < 4; ++rr) {
            int rowq = wm * 64 + mf * 16 + quad * 4 + rr;
            float lsum = 0.0f;
            #pragma unroll
            for (int nf = 0; nf < 4; ++nf) {
                int ckey = wn * 64 + nf * 16 + ln;
                float sc = acc[mf][nf][rr];
                float pe = (diag && ckey > rowq) ? 0.0f : __expf(fminf(sc, 60.0f));
                Pt[rowq * 128 + ckey] = f2bf(pe);
                lsum += pe;
            }
            #pragma unroll
            for (int off = 1; off < 16; off <<= 1)
                lsum += __shfl_xor(lsum, off);
            if (ln == 0) sml[wn][rowq] = lsum;
        }
    __syncthreads();

    if (tid < 128)
        lpart[((size_t)b * PAIRS_ + p) * 128 + tid] = sml[0][tid] + sml[1][tid];
}

// ---------------------------------------------------------------------------
// merge_il: il[b][q] = 1 / sum_kt l_t
// ---------------------------------------------------------------------------
__global__ __launch_bounds__(128) void merge_il(const float* __restrict__ lpart,
                                                float* __restrict__ il) {
    const int qt = blockIdx.x, b = blockIdx.y;
    const int row = threadIdx.x;
    const int pbase = qt * (qt + 1) / 2;
    float l = 0.0f;
    for (int kt = 0; kt <= qt; ++kt)
        l += lpart[((size_t)b * PAIRS_ + pbase + kt) * 128 + row];
    il[(size_t)b * S_ + qt * 128 + row] = 1.0f / l;
}

// ---------------------------------------------------------------------------
// pv_gemm: O = (P @ V) * il.
// NEW: 128q x 256d tiles (P re-fetch factor 8->4), 8 waves (2Mq x 4Nd),
// BK=64 chunks over s, double-buffered source-swizzled LDS, single barrier
// per chunk, setprio. 96 KB LDS, 256 blocks = exactly 1/CU, zero tail.
// PAIRED q-tiles: heavy qt=31-pair then qt=pair -> 66 chunks per block.
// ---------------------------------------------------------------------------
__global__ __launch_bounds__(512, 2) void pv_gemm(
    const unsigned short* __restrict__ P, const unsigned short* __restrict__ Vt,
    const float* __restrict__ il, float* __restrict__ O)
{
    __shared__ __align__(16) unsigned short lsA[2 * 128 * 64];   // 32 KB
    __shared__ __align__(16) unsigned short lsB[2 * 256 * 64];   // 64 KB

    const int l = blockIdx.x;            // 0..255
    const int dt4 = l & 3;               // 256-wide d-slice
    const int u = l >> 2;                // 0..63
    const int pair = u & 15;
    const int b = u >> 4;
    const int d0 = dt4 * 256;
    const int tid = threadIdx.x, lane = tid & 63, w = tid >> 6;
    const int wm = w >> 2, wn = w & 3, quad = lane >> 4, ln = lane & 15;

    const unsigned short* Vtb = Vt + ((size_t)b * D_ + d0) * S_;

    // A: 128 rows x 64-col band (half (c&1)) of P tile kt=c>>1, ld=128
#define PV_STAGE_A(ptile, half, buf)                                                     \
    {                                                                                    \
        _Pragma("unroll")                                                                \
        for (int i_ = 0; i_ < 2; ++i_) {                                                 \
            int g_ = tid + i_ * 512;                                                     \
            int r_ = g_ >> 3;                                                            \
            int cg_ = (g_ & 7) ^ (r_ & 7);                                               \
            gld_lds16((ptile) + (half) * 64 + (size_t)r_ * 128 + cg_ * 8,                \
                      &lsA[(buf) * 8192] + g_ * 8);                                      \
        }                                                                                \
    }
    // B: 256 rows (d) x 64-col band (s offset c*64) of Vt slice, ld=S_
#define PV_STAGE_B(c, buf)                                                               \
    {                                                                                    \
        _Pragma("unroll")                                                                \
        for (int i_ = 0; i_ < 4; ++i_) {                                                 \
            int g_ = tid + i_ * 512;                                                     \
            int r_ = g_ >> 3;                                                            \
            int cg_ = (g_ & 7) ^ (r_ & 7);                                               \
            gld_lds16(Vtb + (size_t)r_ * S_ + (c) * 64 + cg_ * 8,                        \
                      &lsB[(buf) * 16384] + g_ * 8);                                     \
        }                                                                                \
    }

    short8 a[4][2], bfr[4][2];

    #pragma unroll 1
    for (int half = 0; half < 2; ++half) {
        const int qt = half ? pair : (31 - pair);   // heavy first
        const int q0 = qt * 128;
        const int pbase = qt * (qt + 1) / 2;
        const int nc = 2 * (qt + 1);
        const unsigned short* Pbase = P + ((size_t)b * PAIRS_ + pbase) * (128 * 128);

        f32x4 acc[4][4] = {};

        PV_STAGE_A(Pbase, 0, 0)
        PV_STAGE_B(0, 0)
        VM0; SB0;
        BAR; SB0;

        #pragma unroll 1
        for (int c = 0; c < nc; ++c) {
            const int buf = c & 1;
            const unsigned short* As = lsA + buf * 8192;
            const unsigned short* Bs = lsB + buf * 16384;
            if (c + 1 < nc) {
                PV_STAGE_A(Pbase + (size_t)((c + 1) >> 1) * (128 * 128), (c + 1) & 1, buf ^ 1)
                PV_STAGE_B(c + 1, buf ^ 1)
            }
            SB0;
            #pragma unroll
            for (int mf = 0; mf < 4; ++mf)
                #pragma unroll
                for (int ks = 0; ks < 2; ++ks) {
                    int rr_ = wm * 64 + mf * 16 + ln;
                    int cg_ = ks * 4 + quad;
                    a[mf][ks] = *(const short8*)&As[rr_ * 64 + ((cg_ ^ (rr_ & 7)) << 3)];
                }
            #pragma unroll
            for (int nf = 0; nf < 4; ++nf)
                #pragma unroll
                for (int ks = 0; ks < 2; ++ks) {
                    int rr_ = wn * 64 + nf * 16 + ln;
                    int cg_ = ks * 4 + quad;
                    bfr[nf][ks] = *(const short8*)&Bs[rr_ * 64 + ((cg_ ^ (rr_ & 7)) << 3)];
                }
            __builtin_amdgcn_s_setprio(1);
            #pragma unroll
            for (int mf = 0; mf < 4; ++mf)
                #pragma unroll
                for (int nf = 0; nf < 4; ++nf)
                    #pragma unroll
                    for (int ks = 0; ks < 2; ++ks)
                        acc[mf][nf] = __builtin_amdgcn_mfma_f32_16x16x32_bf16(
                            a[mf][ks], bfr[nf][ks], acc[mf][nf], 0, 0, 0);
            __builtin_amdgcn_s_setprio(0);
            LGKM0; SB0;
            VM0; SB0;
            BAR; SB0;
        }

        #pragma unroll
        for (int mf = 0; mf < 4; ++mf) {
            float ilv[4];
            #pragma unroll
            for (int rr = 0; rr < 4; ++rr)
                ilv[rr] = il[(size_t)b * S_ + q0 + wm * 64 + mf * 16 + quad * 4 + rr];
            #pragma unroll
            for (int nf = 0; nf < 4; ++nf)
                #pragma unroll
                for (int rr = 0; rr < 4; ++rr) {
                    int rowq = q0 + wm * 64 + mf * 16 + quad * 4 + rr;
                    int col = d0 + wn * 64 + nf * 16 + ln;
                    O[((size_t)b * S_ + rowq) * D_ + col] = acc[mf][nf][rr] * ilv[rr];
                }
        }
    }
#undef PV_STAGE_A
#undef PV_STAGE_B
}

extern "C" void kernel_launch(void* const* d_in, const int* in_sizes, int n_in,
                              void* d_out, int out_size, void* d_ws, size_t ws_size,
                              hipStream_t stream) {
    const float* x  = (const float*)d_in[0];
    const float* Wq = (const float*)d_in[1];
    const float* Wk = (const float*)d_in[2];
    const float* Wv = (const float*)d_in[3];

    const size_t nQ = (size_t)B_ * S_ * D_;
    const size_t nP = (size_t)B_ * PAIRS_ * 128 * 128;

    unsigned short* P  = (unsigned short*)d_ws;
    unsigned short* V  = P;                       // alias: dead before P written
    unsigned short* Q  = P + nP;
    unsigned short* K  = Q + nQ;
    unsigned short* Vt = K + nQ;
    unsigned short* xb = Vt;                      // alias: dead before Vt written
    unsigned short* Wt = Vt + nQ;
    float* lpart = (float*)(Wt + (size_t)3 * D_ * D_);
    float* il    = lpart + (size_t)B_ * PAIRS_ * 128;
    float* O = (float*)d_out;

    hipLaunchKernelGGL(prep_x, dim3(8192), dim3(256), 0, stream, x, xb);
    hipLaunchKernelGGL(prep_w, dim3(16, 16, 3), dim3(256), 0, stream, Wq, Wk, Wv, Wt);
    hipLaunchKernelGGL(qkv_gemm, dim3(256, 1, 3), dim3(512), 0, stream, xb, Wt, Q, K, V);
    hipLaunchKernelGGL(vt_trans, dim3(64, 16, B_), dim3(256), 0, stream, V, Vt);
    hipLaunchKernelGGL(qk_pexp, dim3(PAIRS_, B_), dim3(256), 0, stream, Q, K, P, lpart);
    hipLaunchKernelGGL(merge_il, dim3(NT_, B_), dim3(128), 0, stream, lpart, il);
    hipLaunchKernelGGL(pv_gemm, dim3(256), dim3(512), 0, stream, P, Vt, il, O);
}

// Round 4
// 424.145 us; speedup vs baseline: 1.0796x; 1.0133x over previous
//
#include <hip/hip_runtime.h>
#include <hip/hip_bf16.h>

#define B_ 4
#define S_ 4096
#define D_ 1024
#define NT_ 32        // S_/128
#define PAIRS_ 528    // NT_*(NT_+1)/2 lower-triangle tile pairs

typedef __attribute__((ext_vector_type(8))) short short8;
typedef __attribute__((ext_vector_type(4))) float f32x4;

__device__ __forceinline__ unsigned short f2bf(float f) {
    union { float f; unsigned u; } v; v.f = f;
    unsigned u = v.u;
    return (unsigned short)((u + 0x7fffu + ((u >> 16) & 1u)) >> 16);
}

// async global->LDS, 16B per lane. LDS dst is wave-uniform base + lane*16.
__device__ __forceinline__ void gld_lds16(const unsigned short* g, unsigned short* l) {
    __builtin_amdgcn_global_load_lds((const __attribute__((address_space(1))) void*)g,
                                     (__attribute__((address_space(3))) void*)l, 16, 0, 0);
}

#define LGKM0 asm volatile("s_waitcnt lgkmcnt(0)" ::: "memory")
#define VM0   asm volatile("s_waitcnt vmcnt(0)" ::: "memory")
#define BAR   __builtin_amdgcn_s_barrier()
#define SB0   __builtin_amdgcn_sched_barrier(0)

// ---------------------------------------------------------------------------
// prep_x: fp32 x -> bf16 xb
// ---------------------------------------------------------------------------
__global__ __launch_bounds__(256) void prep_x(const float* __restrict__ x,
                                              unsigned short* __restrict__ xb) {
    size_t i = ((size_t)blockIdx.x * 256 + threadIdx.x) * 8;
    float4 a = *(const float4*)&x[i];
    float4 b = *(const float4*)&x[i + 4];
    unsigned u0 = (unsigned)f2bf(a.x) | ((unsigned)f2bf(a.y) << 16);
    unsigned u1 = (unsigned)f2bf(a.z) | ((unsigned)f2bf(a.w) << 16);
    unsigned u2 = (unsigned)f2bf(b.x) | ((unsigned)f2bf(b.y) << 16);
    unsigned u3 = (unsigned)f2bf(b.z) | ((unsigned)f2bf(b.w) << 16);
    uint4 val; val.x = u0; val.y = u1; val.z = u2; val.w = u3;
    *(uint4*)&xb[i] = val;
}

// ---------------------------------------------------------------------------
// prep_w: W[k][n] fp32 -> Wt[n][k] bf16
// ---------------------------------------------------------------------------
__global__ __launch_bounds__(256) void prep_w(const float* __restrict__ Wq,
                                              const float* __restrict__ Wk,
                                              const float* __restrict__ Wv,
                                              unsigned short* __restrict__ Wt) {
    __shared__ float ls[64 * 65];
    const int z = blockIdx.z;
    const float* __restrict__ W = (z == 0) ? Wq : (z == 1) ? Wk : Wv;
    unsigned short* __restrict__ Wtz = Wt + (size_t)z * D_ * D_;
    const int k0 = blockIdx.y * 64, n0 = blockIdx.x * 64;
    const int tid = threadIdx.x;
    #pragma unroll
    for (int i = 0; i < 16; ++i) {
        int lin = i * 256 + tid, r = lin >> 6, c = lin & 63;
        ls[r * 65 + c] = W[(size_t)(k0 + r) * D_ + n0 + c];
    }
    __syncthreads();
    #pragma unroll
    for (int i = 0; i < 16; ++i) {
        int lin = i * 256 + tid, r = lin >> 6, c = lin & 63;
        Wtz[(size_t)(n0 + r) * D_ + k0 + c] = f2bf(ls[c * 65 + r]);
    }
}

// ---------------------------------------------------------------------------
// qkv_gemm: Y = xb @ Wt_z^T.  256x256, BK=64, 8 waves, source-swizzled LDS,
// single barrier/K-tile, setprio. NEW: B fragments fully resident (b[4][2],
// 8 ds_reads) so the tile body does 24 LDS reads instead of 28.
// ---------------------------------------------------------------------------
__global__ __launch_bounds__(512, 2) void qkv_gemm(
    const unsigned short* __restrict__ xb, const unsigned short* __restrict__ Wt,
    unsigned short* __restrict__ Q, unsigned short* __restrict__ K,
    unsigned short* __restrict__ V)
{
    __shared__ __align__(16) unsigned short lsA[2 * 256 * 64];   // 64 KiB
    __shared__ __align__(16) unsigned short lsB[2 * 256 * 64];   // 64 KiB

    const int z = blockIdx.z;
    unsigned short* __restrict__ Y = (z == 0) ? Q : (z == 1) ? K : V;
    const float scale = (z == 0) ? 0.03125f : 1.0f;

    const int lin = blockIdx.x;                       // 0..255
    const int wg = (lin & 7) * 32 + (lin >> 3);
    const int m0 = (wg >> 2) * 256, n0 = (wg & 3) * 256;

    const int tid = threadIdx.x, lane = tid & 63, w = tid >> 6;
    const int wm = w >> 2, wn = w & 3;                // 2 x 4 wave grid
    const int quad = lane >> 4, ln = lane & 15;

    const unsigned short* Ab = xb + (size_t)m0 * D_;
    const unsigned short* Bb = Wt + (size_t)z * D_ * D_ + (size_t)n0 * D_;

#define STAGE_HALF(gbase, ldsbase)                                              \
    {                                                                           \
        _Pragma("unroll")                                                       \
        for (int i_ = 0; i_ < 2; ++i_) {                                        \
            int g_ = tid + i_ * 512;                                            \
            int r_ = g_ >> 3;                                                   \
            int cg_ = (g_ & 7) ^ (r_ & 7);                                      \
            gld_lds16((gbase) + (size_t)r_ * D_ + cg_ * 8, (ldsbase) + g_ * 8); \
        }                                                                       \
    }
#define STAGE(kt, h)                                                                   \
    {                                                                                  \
        if ((h) < 2) { STAGE_HALF(Ab + (size_t)((h) * 128) * D_ + (kt) * 64,           \
                                  &lsA[(((kt) & 1) * 2 + (h)) * 8192]) }               \
        else         { STAGE_HALF(Bb + (size_t)(((h) - 2) * 128) * D_ + (kt) * 64,     \
                                  &lsB[(((kt) & 1) * 2 + ((h) - 2)) * 8192]) }         \
    }

    const unsigned short* As;
    const unsigned short* Bs;
    short8 a[4][2], b[4][2];
    f32x4 acc[8][4] = {};

#define LDA(mh)                                                                        \
    {                                                                                  \
        _Pragma("unroll")                                                              \
        for (int mf_ = 0; mf_ < 4; ++mf_) {                                            \
            _Pragma("unroll")                                                          \
            for (int ks_ = 0; ks_ < 2; ++ks_) {                                        \
                int r_ = wm * 128 + ((mh) * 4 + mf_) * 16 + ln;                        \
                int cg_ = ks_ * 4 + quad;                                              \
                a[mf_][ks_] = *(const short8*)&As[r_ * 64 + ((cg_ ^ (r_ & 7)) << 3)];  \
            }                                                                          \
        }                                                                              \
    }
#define LDB_ALL                                                                        \
    {                                                                                  \
        _Pragma("unroll")                                                              \
        for (int nf_ = 0; nf_ < 4; ++nf_) {                                            \
            _Pragma("unroll")                                                          \
            for (int ks_ = 0; ks_ < 2; ++ks_) {                                        \
                int r_ = wn * 64 + nf_ * 16 + ln;                                      \
                int cg_ = ks_ * 4 + quad;                                              \
                b[nf_][ks_] = *(const short8*)&Bs[r_ * 64 + ((cg_ ^ (r_ & 7)) << 3)];  \
            }                                                                          \
        }                                                                              \
    }
#define MM_H(mh)                                                                       \
    {                                                                                  \
        __builtin_amdgcn_s_setprio(1);                                                 \
        _Pragma("unroll")                                                              \
        for (int mf_ = 0; mf_ < 4; ++mf_)                                              \
            _Pragma("unroll")                                                          \
            for (int nf_ = 0; nf_ < 4; ++nf_)                                          \
                _Pragma("unroll")                                                      \
                for (int ks_ = 0; ks_ < 2; ++ks_)                                      \
                    acc[(mh) * 4 + mf_][nf_] =                                         \
                        __builtin_amdgcn_mfma_f32_16x16x32_bf16(                       \
                            a[mf_][ks_], b[nf_][ks_],                                  \
                            acc[(mh) * 4 + mf_][nf_], 0, 0, 0);                        \
        __builtin_amdgcn_s_setprio(0);                                                 \
    }

    STAGE(0, 0) STAGE(0, 1) STAGE(0, 2) STAGE(0, 3)
    VM0; SB0;
    BAR; SB0;

    #pragma unroll 2
    for (int t = 0; t < 16; ++t) {
        As = lsA + (t & 1) * 16384;
        Bs = lsB + (t & 1) * 16384;
        if (t < 15) { STAGE(t + 1, 0) STAGE(t + 1, 1) STAGE(t + 1, 2) STAGE(t + 1, 3) }
        SB0;
        LDA(0) LDB_ALL
        MM_H(0)
        LDA(1)
        MM_H(1)
        LGKM0; SB0;
        if (t < 15) {
            VM0; SB0;
            BAR; SB0;
        }
    }

#undef STAGE_HALF
#undef STAGE
#undef LDA
#undef LDB_ALL
#undef MM_H

    #pragma unroll
    for (int mf = 0; mf < 8; ++mf)
        #pragma unroll
        for (int nf = 0; nf < 4; ++nf)
            #pragma unroll
            for (int rr = 0; rr < 4; ++rr) {
                int row = m0 + wm * 128 + mf * 16 + quad * 4 + rr;
                int col = n0 + wn * 64 + nf * 16 + ln;
                Y[(size_t)row * D_ + col] = f2bf(acc[mf][nf][rr] * scale);
            }
}

// ---------------------------------------------------------------------------
// vt_trans: V[b][s][e] -> Vt[b][e][s]
// ---------------------------------------------------------------------------
__global__ __launch_bounds__(256) void vt_trans(const unsigned short* __restrict__ V,
                                                unsigned short* __restrict__ Vt) {
    __shared__ unsigned short ls[64 * 66];
    const int s0 = blockIdx.x * 64, e0 = blockIdx.y * 64, b = blockIdx.z;
    const int tid = threadIdx.x;
    const size_t base = (size_t)b * S_ * D_;
    #pragma unroll
    for (int i = 0; i < 16; ++i) {
        int lin = i * 256 + tid, r = lin >> 6, c = lin & 63;
        ls[r * 66 + c] = V[base + (size_t)(s0 + r) * D_ + e0 + c];
    }
    __syncthreads();
    const size_t baseT = (size_t)b * D_ * S_;
    #pragma unroll
    for (int i = 0; i < 16; ++i) {
        int lin = i * 256 + tid, r = lin >> 6, c = lin & 63;
        Vt[baseT + (size_t)(e0 + r) * S_ + s0 + c] = ls[c * 66 + r];
    }
}

// ---------------------------------------------------------------------------
// qk_pexp: per lower-tri tile pair: P = exp(Q@K^T) bf16 tile-packed, partial l.
// BK=64 double-buffered, source-swizzled staging + swizzled ds_read, single
// barrier per K-tile, setprio. 4 waves, 65 KB LDS -> 2 blocks/CU.
// XCD-swizzled: XCD r owns qt rows {r, 31-r, 8+r, 23-r} (66 blocks each).
// ---------------------------------------------------------------------------
__global__ __launch_bounds__(256, 2) void qk_pexp(
    const unsigned short* __restrict__ Q, const unsigned short* __restrict__ K,
    unsigned short* __restrict__ P, float* __restrict__ lpart)
{
    __shared__ __align__(16) unsigned short lsA[2 * 128 * 64];   // 32 KB
    __shared__ __align__(16) unsigned short lsB[2 * 128 * 64];   // 32 KB
    __shared__ float sml[2][128];

    const int l = blockIdx.x, b = blockIdx.y;
    const int r = l & 7;          // xcd
    const int s = l >> 3;         // 0..65
    int qt, kt;
    if (s < r + 1)            { qt = r;      kt = s; }
    else if (s < 33)          { qt = 31 - r; kt = s - (r + 1); }
    else if (s < 42 + r)      { qt = 8 + r;  kt = s - 33; }
    else                      { qt = 23 - r; kt = s - (42 + r); }
    const int p = qt * (qt + 1) / 2 + kt;

    const int q0 = qt * 128, k0 = kt * 128;
    const int tid = threadIdx.x, lane = tid & 63, w = tid >> 6;
    const int wm = w >> 1, wn = w & 1, quad = lane >> 4, ln = lane & 15;
    const size_t base = (size_t)b * S_ * D_;

    const unsigned short* Qb = Q + base + (size_t)q0 * D_;
    const unsigned short* Kb = K + base + (size_t)k0 * D_;

#define QK_STAGE_HALF(gbase, ldsbase)                                           \
    {                                                                           \
        _Pragma("unroll")                                                       \
        for (int i_ = 0; i_ < 4; ++i_) {                                        \
            int g_ = tid + i_ * 256;                                            \
            int r_ = g_ >> 3;                                                   \
            int cg_ = (g_ & 7) ^ (r_ & 7);                                      \
            gld_lds16((gbase) + (size_t)r_ * D_ + cg_ * 8, (ldsbase) + g_ * 8); \
        }                                                                       \
    }
#define QK_STAGE(t)                                                             \
    {                                                                           \
        QK_STAGE_HALF(Qb + (t) * 64, &lsA[((t) & 1) * 8192])                    \
        QK_STAGE_HALF(Kb + (t) * 64, &lsB[((t) & 1) * 8192])                    \
    }

    short8 a[4][2], bfr[4][2];
    f32x4 acc[4][4] = {};

    QK_STAGE(0)
    VM0; SB0;
    BAR; SB0;

    #pragma unroll 2
    for (int t = 0; t < 16; ++t) {
        const unsigned short* As = lsA + (t & 1) * 8192;
        const unsigned short* Bs = lsB + (t & 1) * 8192;
        if (t < 15) QK_STAGE(t + 1)
        SB0;
        #pragma unroll
        for (int mf = 0; mf < 4; ++mf)
            #pragma unroll
            for (int ks = 0; ks < 2; ++ks) {
                int rr_ = wm * 64 + mf * 16 + ln;
                int cg_ = ks * 4 + quad;
                a[mf][ks] = *(const short8*)&As[rr_ * 64 + ((cg_ ^ (rr_ & 7)) << 3)];
            }
        #pragma unroll
        for (int nf = 0; nf < 4; ++nf)
            #pragma unroll
            for (int ks = 0; ks < 2; ++ks) {
                int rr_ = wn * 64 + nf * 16 + ln;
                int cg_ = ks * 4 + quad;
                bfr[nf][ks] = *(const short8*)&Bs[rr_ * 64 + ((cg_ ^ (rr_ & 7)) << 3)];
            }
        __builtin_amdgcn_s_setprio(1);
        #pragma unroll
        for (int mf = 0; mf < 4; ++mf)
            #pragma unroll
            for (int nf = 0; nf < 4; ++nf)
                #pragma unroll
                for (int ks = 0; ks < 2; ++ks)
                    acc[mf][nf] = __builtin_amdgcn_mfma_f32_16x16x32_bf16(
                        a[mf][ks], bfr[nf][ks], acc[mf][nf], 0, 0, 0);
        __builtin_amdgcn_s_setprio(0);
        LGKM0; SB0;
        if (t < 15) {
            VM0; SB0;
            BAR; SB0;
        }
    }
#undef QK_STAGE_HALF
#undef QK_STAGE

    const bool diag = (kt == qt);
    unsigned short* Pt = P + ((size_t)b * PAIRS_ + p) * (128 * 128);

    #pragma unroll
    for (int mf = 0; mf < 4; ++mf)
        #pragma unroll
        for (int rr = 0; rr < 4; ++rr) {
            int rowq = wm * 64 + mf * 16 + quad * 4 + rr;
            float lsum = 0.0f;
            #pragma unroll
            for (int nf = 0; nf < 4; ++nf) {
                int ckey = wn * 64 + nf * 16 + ln;
                float sc = acc[mf][nf][rr];
                float pe = (diag && ckey > rowq) ? 0.0f : __expf(fminf(sc, 60.0f));
                Pt[rowq * 128 + ckey] = f2bf(pe);
                lsum += pe;
            }
            #pragma unroll
            for (int off = 1; off < 16; off <<= 1)
                lsum += __shfl_xor(lsum, off);
            if (ln == 0) sml[wn][rowq] = lsum;
        }
    __syncthreads();

    if (tid < 128)
        lpart[((size_t)b * PAIRS_ + p) * 128 + tid] = sml[0][tid] + sml[1][tid];
}

// ---------------------------------------------------------------------------
// merge_il: il[b][q] = 1 / sum_kt l_t
// ---------------------------------------------------------------------------
__global__ __launch_bounds__(128) void merge_il(const float* __restrict__ lpart,
                                                float* __restrict__ il) {
    const int qt = blockIdx.x, b = blockIdx.y;
    const int row = threadIdx.x;
    const int pbase = qt * (qt + 1) / 2;
    float l = 0.0f;
    for (int kt = 0; kt <= qt; ++kt)
        l += lpart[((size_t)b * PAIRS_ + pbase + kt) * 128 + row];
    il[(size_t)b * S_ + qt * 128 + row] = 1.0f / l;
}

// ---------------------------------------------------------------------------
// pv_gemm: O = (P @ V) * il.
// NEW: 128q x 128d tiles, 4 waves, 64 KB LDS -> 2 blocks/CU (two independent
// barrier domains per CU overlap each other's staging). 512 blocks, exact
// pair balance. XCD-SIBLING remap: all 8 d-slices of a (b,pair) share one
// XCD (bid%8 == u%8) so the P tiles are fetched into that XCD's L2 ONCE and
// shared 8 ways (P is L3-resident; this kills the 4-8x L2-fill refetch).
// ---------------------------------------------------------------------------
__global__ __launch_bounds__(256, 2) void pv_gemm(
    const unsigned short* __restrict__ P, const unsigned short* __restrict__ Vt,
    const float* __restrict__ il, float* __restrict__ O)
{
    __shared__ __align__(16) unsigned short lsA[2 * 128 * 64];   // 32 KB
    __shared__ __align__(16) unsigned short lsB[2 * 128 * 64];   // 32 KB

    const int bid = blockIdx.x;                      // 0..511
    const int u  = (bid & 7) | ((bid >> 6) << 3);    // 0..63  (b*16+pair)
    const int dt = (bid >> 3) & 7;                   // 0..7   d-slice
    const int pair = u & 15;
    const int b = u >> 4;
    const int d0 = dt * 128;
    const int tid = threadIdx.x, lane = tid & 63, w = tid >> 6;
    const int wm = w >> 1, wn = w & 1, quad = lane >> 4, ln = lane & 15;

    const unsigned short* Vtb = Vt + ((size_t)b * D_ + d0) * S_;

    // A: 128 rows x 64-col band (half (c&1)) of P tile kt=c>>1, ld=128
#define PV_STAGE_A(ptile, half, buf)                                                     \
    {                                                                                    \
        _Pragma("unroll")                                                                \
        for (int i_ = 0; i_ < 4; ++i_) {                                                 \
            int g_ = tid + i_ * 256;                                                     \
            int r_ = g_ >> 3;                                                            \
            int cg_ = (g_ & 7) ^ (r_ & 7);                                               \
            gld_lds16((ptile) + (half) * 64 + (size_t)r_ * 128 + cg_ * 8,                \
                      &lsA[(buf) * 8192] + g_ * 8);                                      \
        }                                                                                \
    }
    // B: 128 rows (d) x 64-col band (s offset c*64) of Vt slice, ld=S_
#define PV_STAGE_B(c, buf)                                                               \
    {                                                                                    \
        _Pragma("unroll")                                                                \
        for (int i_ = 0; i_ < 4; ++i_) {                                                 \
            int g_ = tid + i_ * 256;                                                     \
            int r_ = g_ >> 3;                                                            \
            int cg_ = (g_ & 7) ^ (r_ & 7);                                               \
            gld_lds16(Vtb + (size_t)r_ * S_ + (c) * 64 + cg_ * 8,                        \
                      &lsB[(buf) * 8192] + g_ * 8);                                      \
        }                                                                                \
    }

    short8 a[4][2], bfr[4][2];

    #pragma unroll 1
    for (int half = 0; half < 2; ++half) {
        const int qt = half ? pair : (31 - pair);   // heavy first
        const int q0 = qt * 128;
        const int pbase = qt * (qt + 1) / 2;
        const int nc = 2 * (qt + 1);
        const unsigned short* Pbase = P + ((size_t)b * PAIRS_ + pbase) * (128 * 128);

        f32x4 acc[4][4] = {};

        PV_STAGE_A(Pbase, 0, 0)
        PV_STAGE_B(0, 0)
        VM0; SB0;
        BAR; SB0;

        #pragma unroll 1
        for (int c = 0; c < nc; ++c) {
            const int buf = c & 1;
            const unsigned short* As = lsA + buf * 8192;
            const unsigned short* Bs = lsB + buf * 8192;
            if (c + 1 < nc) {
                PV_STAGE_A(Pbase + (size_t)((c + 1) >> 1) * (128 * 128), (c + 1) & 1, buf ^ 1)
                PV_STAGE_B(c + 1, buf ^ 1)
            }
            SB0;
            #pragma unroll
            for (int mf = 0; mf < 4; ++mf)
                #pragma unroll
                for (int ks = 0; ks < 2; ++ks) {
                    int rr_ = wm * 64 + mf * 16 + ln;
                    int cg_ = ks * 4 + quad;
                    a[mf][ks] = *(const short8*)&As[rr_ * 64 + ((cg_ ^ (rr_ & 7)) << 3)];
                }
            #pragma unroll
            for (int nf = 0; nf < 4; ++nf)
                #pragma unroll
                for (int ks = 0; ks < 2; ++ks) {
                    int rr_ = wn * 64 + nf * 16 + ln;
                    int cg_ = ks * 4 + quad;
                    bfr[nf][ks] = *(const short8*)&Bs[rr_ * 64 + ((cg_ ^ (rr_ & 7)) << 3)];
                }
            __builtin_amdgcn_s_setprio(1);
            #pragma unroll
            for (int mf = 0; mf < 4; ++mf)
                #pragma unroll
                for (int nf = 0; nf < 4; ++nf)
                    #pragma unroll
                    for (int ks = 0; ks < 2; ++ks)
                        acc[mf][nf] = __builtin_amdgcn_mfma_f32_16x16x32_bf16(
                            a[mf][ks], bfr[nf][ks], acc[mf][nf], 0, 0, 0);
            __builtin_amdgcn_s_setprio(0);
            LGKM0; SB0;
            VM0; SB0;
            BAR; SB0;
        }

        #pragma unroll
        for (int mf = 0; mf < 4; ++mf) {
            float ilv[4];
            #pragma unroll
            for (int rr = 0; rr < 4; ++rr)
                ilv[rr] = il[(size_t)b * S_ + q0 + wm * 64 + mf * 16 + quad * 4 + rr];
            #pragma unroll
            for (int nf = 0; nf < 4; ++nf)
                #pragma unroll
                for (int rr = 0; rr < 4; ++rr) {
                    int rowq = q0 + wm * 64 + mf * 16 + quad * 4 + rr;
                    int col = d0 + wn * 64 + nf * 16 + ln;
                    O[((size_t)b * S_ + rowq) * D_ + col] = acc[mf][nf][rr] * ilv[rr];
                }
        }
    }
#undef PV_STAGE_A
#undef PV_STAGE_B
}

extern "C" void kernel_launch(void* const* d_in, const int* in_sizes, int n_in,
                              void* d_out, int out_size, void* d_ws, size_t ws_size,
                              hipStream_t stream) {
    const float* x  = (const float*)d_in[0];
    const float* Wq = (const float*)d_in[1];
    const float* Wk = (const float*)d_in[2];
    const float* Wv = (const float*)d_in[3];

    const size_t nQ = (size_t)B_ * S_ * D_;
    const size_t nP = (size_t)B_ * PAIRS_ * 128 * 128;

    unsigned short* P  = (unsigned short*)d_ws;
    unsigned short* V  = P;                       // alias: dead before P written
    unsigned short* Q  = P + nP;
    unsigned short* K  = Q + nQ;
    unsigned short* Vt = K + nQ;
    unsigned short* xb = Vt;                      // alias: dead before Vt written
    unsigned short* Wt = Vt + nQ;
    float* lpart = (float*)(Wt + (size_t)3 * D_ * D_);
    float* il    = lpart + (size_t)B_ * PAIRS_ * 128;
    float* O = (float*)d_out;

    hipLaunchKernelGGL(prep_x, dim3(8192), dim3(256), 0, stream, x, xb);
    hipLaunchKernelGGL(prep_w, dim3(16, 16, 3), dim3(256), 0, stream, Wq, Wk, Wv, Wt);
    hipLaunchKernelGGL(qkv_gemm, dim3(256, 1, 3), dim3(512), 0, stream, xb, Wt, Q, K, V);
    hipLaunchKernelGGL(vt_trans, dim3(64, 16, B_), dim3(256), 0, stream, V, Vt);
    hipLaunchKernelGGL(qk_pexp, dim3(PAIRS_, B_), dim3(256), 0, stream, Q, K, P, lpart);
    hipLaunchKernelGGL(merge_il, dim3(NT_, B_), dim3(128), 0, stream, lpart, il);
    hipLaunchKernelGGL(pv_gemm, dim3(512), dim3(256), 0, stream, P, Vt, il, O);
}

// Round 5
// 423.724 us; speedup vs baseline: 1.0807x; 1.0010x over previous
//
#include <hip/hip_runtime.h>
#include <hip/hip_bf16.h>

#define B_ 4
#define S_ 4096
#define D_ 1024
#define NT_ 32        // S_/128
#define PAIRS_ 528    // NT_*(NT_+1)/2 lower-triangle tile pairs

typedef __attribute__((ext_vector_type(8))) short short8;
typedef __attribute__((ext_vector_type(4))) float f32x4;

__device__ __forceinline__ unsigned short f2bf(float f) {
    union { float f; unsigned u; } v; v.f = f;
    unsigned u = v.u;
    return (unsigned short)((u + 0x7fffu + ((u >> 16) & 1u)) >> 16);
}

// async global->LDS, 16B per lane. LDS dst is wave-uniform base + lane*16.
__device__ __forceinline__ void gld_lds16(const unsigned short* g, unsigned short* l) {
    __builtin_amdgcn_global_load_lds((const __attribute__((address_space(1))) void*)g,
                                     (__attribute__((address_space(3))) void*)l, 16, 0, 0);
}

#define LGKM0 asm volatile("s_waitcnt lgkmcnt(0)" ::: "memory")
#define VM0   asm volatile("s_waitcnt vmcnt(0)" ::: "memory")
#define VM4   asm volatile("s_waitcnt vmcnt(4)" ::: "memory")
#define BAR   __builtin_amdgcn_s_barrier()
#define SB0   __builtin_amdgcn_sched_barrier(0)

// ---------------------------------------------------------------------------
// prep_x: fp32 x -> bf16 xb
// ---------------------------------------------------------------------------
__global__ __launch_bounds__(256) void prep_x(const float* __restrict__ x,
                                              unsigned short* __restrict__ xb) {
    size_t i = ((size_t)blockIdx.x * 256 + threadIdx.x) * 8;
    float4 a = *(const float4*)&x[i];
    float4 b = *(const float4*)&x[i + 4];
    unsigned u0 = (unsigned)f2bf(a.x) | ((unsigned)f2bf(a.y) << 16);
    unsigned u1 = (unsigned)f2bf(a.z) | ((unsigned)f2bf(a.w) << 16);
    unsigned u2 = (unsigned)f2bf(b.x) | ((unsigned)f2bf(b.y) << 16);
    unsigned u3 = (unsigned)f2bf(b.z) | ((unsigned)f2bf(b.w) << 16);
    uint4 val; val.x = u0; val.y = u1; val.z = u2; val.w = u3;
    *(uint4*)&xb[i] = val;
}

// ---------------------------------------------------------------------------
// prep_w: W[k][n] fp32 -> Wt[n][k] bf16
// ---------------------------------------------------------------------------
__global__ __launch_bounds__(256) void prep_w(const float* __restrict__ Wq,
                                              const float* __restrict__ Wk,
                                              const float* __restrict__ Wv,
                                              unsigned short* __restrict__ Wt) {
    __shared__ float ls[64 * 65];
    const int z = blockIdx.z;
    const float* __restrict__ W = (z == 0) ? Wq : (z == 1) ? Wk : Wv;
    unsigned short* __restrict__ Wtz = Wt + (size_t)z * D_ * D_;
    const int k0 = blockIdx.y * 64, n0 = blockIdx.x * 64;
    const int tid = threadIdx.x;
    #pragma unroll
    for (int i = 0; i < 16; ++i) {
        int lin = i * 256 + tid, r = lin >> 6, c = lin & 63;
        ls[r * 65 + c] = W[(size_t)(k0 + r) * D_ + n0 + c];
    }
    __syncthreads();
    #pragma unroll
    for (int i = 0; i < 16; ++i) {
        int lin = i * 256 + tid, r = lin >> 6, c = lin & 63;
        Wtz[(size_t)(n0 + r) * D_ + k0 + c] = f2bf(ls[c * 65 + r]);
    }
}

// ---------------------------------------------------------------------------
// qkv_gemm: Y = xb @ Wt_z^T.  256x256 tile, 8 waves (2x4).
// NEW: BK=32 ring-of-3 LDS buffers (96 KB), stage 2 steps ahead, counted
// boundary wait vmcnt(4) (never drains to 0 in steady state, m218/T4).
// BK=32 swizzle: 16B-granule index ^= (row>>1)&3 (2-way only = free), applied
// inverse on global source + forward on ds_read (rule #21).
// z==2 writes Vt DIRECTLY via per-wave LDS transpose (vt_trans kernel gone).
// ---------------------------------------------------------------------------
__global__ __launch_bounds__(512, 2) void qkv_gemm(
    const unsigned short* __restrict__ xb, const unsigned short* __restrict__ Wt,
    unsigned short* __restrict__ Q, unsigned short* __restrict__ K,
    unsigned short* __restrict__ Vt)
{
    __shared__ __align__(16) unsigned short ls[3 * 16384];   // 96 KiB ring

    const int z = blockIdx.z;
    const float scale = (z == 0) ? 0.03125f : 1.0f;

    const int lin = blockIdx.x;                       // 0..255
    const int wg = (lin & 7) * 32 + (lin >> 3);       // XCD-contiguous
    const int m0 = (wg >> 2) * 256, n0 = (wg & 3) * 256;

    const int tid = threadIdx.x, lane = tid & 63, w = tid >> 6;
    const int wm = w >> 2, wn = w & 3;                // 2 x 4 wave grid
    const int quad = lane >> 4, ln = lane & 15;

    const unsigned short* Ab = xb + (size_t)m0 * D_;
    const unsigned short* Bb = Wt + (size_t)z * D_ * D_ + (size_t)n0 * D_;

    // stage K-step kt (256 rows x 32 cols each of A and B) into ring buf r.
    // 4 loads/thread.  linear granule g: row=g>>2, slot=g&3, src granule =
    // slot ^ ((row>>1)&3).
#define QKV_STAGE(kt, r)                                                          \
    {                                                                             \
        _Pragma("unroll")                                                         \
        for (int i_ = 0; i_ < 2; ++i_) {                                          \
            int g_ = tid + i_ * 512;                                              \
            int row_ = g_ >> 2;                                                   \
            int gs_ = (g_ & 3) ^ ((row_ >> 1) & 3);                               \
            gld_lds16(Ab + (size_t)row_ * D_ + (kt) * 32 + gs_ * 8,               \
                      ls + (r) * 16384 + g_ * 8);                                 \
            gld_lds16(Bb + (size_t)row_ * D_ + (kt) * 32 + gs_ * 8,               \
                      ls + (r) * 16384 + 8192 + g_ * 8);                          \
        }                                                                         \
    }

    f32x4 acc[8][4] = {};

#define QKV_BODY(r)                                                              \
    {                                                                            \
        const unsigned short* As_ = ls + (r) * 16384;                            \
        const unsigned short* Bs_ = As_ + 8192;                                  \
        short8 a_[8], b_[4];                                                     \
        _Pragma("unroll")                                                        \
        for (int mf_ = 0; mf_ < 8; ++mf_) {                                      \
            int row_ = wm * 128 + mf_ * 16 + ln;                                 \
            int g_ = quad ^ ((row_ >> 1) & 3);                                   \
            a_[mf_] = *(const short8*)&As_[row_ * 32 + g_ * 8];                  \
        }                                                                        \
        _Pragma("unroll")                                                        \
        for (int nf_ = 0; nf_ < 4; ++nf_) {                                      \
            int row_ = wn * 64 + nf_ * 16 + ln;                                  \
            int g_ = quad ^ ((row_ >> 1) & 3);                                   \
            b_[nf_] = *(const short8*)&Bs_[row_ * 32 + g_ * 8];                  \
        }                                                                        \
        __builtin_amdgcn_s_setprio(1);                                          \
        _Pragma("unroll")                                                        \
        for (int mf_ = 0; mf_ < 8; ++mf_)                                        \
            _Pragma("unroll")                                                    \
            for (int nf_ = 0; nf_ < 4; ++nf_)                                    \
                acc[mf_][nf_] = __builtin_amdgcn_mfma_f32_16x16x32_bf16(         \
                    a_[mf_], b_[nf_], acc[mf_][nf_], 0, 0, 0);                   \
        __builtin_amdgcn_s_setprio(0);                                          \
    }

    // wcode 0: steady (stage t+2, vmcnt(4), BAR); 1: t==30 (VM0, BAR); 2: last
#define QKV_STEP(t, r, rn, wcode)                                                \
    {                                                                            \
        if ((wcode) == 0) QKV_STAGE((t) + 2, rn)                                 \
        SB0;                                                                     \
        QKV_BODY(r)                                                              \
        LGKM0; SB0;                                                              \
        if ((wcode) == 0)      { VM4; SB0; BAR; SB0; }                           \
        else if ((wcode) == 1) { VM0; SB0; BAR; SB0; }                           \
    }

    QKV_STAGE(0, 0) QKV_STAGE(1, 1)
    VM4; SB0;
    BAR; SB0;

    #pragma unroll 1
    for (int tb = 0; tb < 30; tb += 3) {
        QKV_STEP(tb,     0, 2, 0)
        QKV_STEP(tb + 1, 1, 0, 0)
        QKV_STEP(tb + 2, 2, 1, 0)
    }
    QKV_STEP(30, 0, 0, 1)
    QKV_STEP(31, 1, 0, 2)

#undef QKV_STAGE
#undef QKV_BODY
#undef QKV_STEP

    if (z != 2) {
        unsigned short* __restrict__ Y = (z == 0) ? Q : K;
        #pragma unroll
        for (int mf = 0; mf < 8; ++mf)
            #pragma unroll
            for (int nf = 0; nf < 4; ++nf)
                #pragma unroll
                for (int rr = 0; rr < 4; ++rr) {
                    int row = m0 + wm * 128 + mf * 16 + quad * 4 + rr;
                    int col = n0 + wn * 64 + nf * 16 + ln;
                    Y[(size_t)row * D_ + col] = f2bf(acc[mf][nf][rr] * scale);
                }
    } else {
        // transposed store: Vt[b][e][s].  Per-wave LDS transpose, packed u32.
        BAR;                                   // all waves done with ring reads
        unsigned int* U = (unsigned int*)ls + w * 2080;     // [32 e][65 u32]
        const int b_ = m0 >> 12;                            // batch
        const int sbase = (m0 & 4095) + wm * 128;           // s within batch
        unsigned int* VtU = (unsigned int*)Vt;
        #pragma unroll
        for (int ch = 0; ch < 2; ++ch) {
            #pragma unroll
            for (int nfl = 0; nfl < 2; ++nfl) {
                int nf = ch * 2 + nfl;
                int el = nfl * 16 + ln;
                #pragma unroll
                for (int mf = 0; mf < 8; ++mf)
                    #pragma unroll
                    for (int pr = 0; pr < 2; ++pr) {
                        unsigned lo = f2bf(acc[mf][nf][2 * pr]);
                        unsigned hi = f2bf(acc[mf][nf][2 * pr + 1]);
                        U[el * 65 + mf * 8 + quad * 2 + pr] = lo | (hi << 16);
                    }
            }
            LGKM0; SB0;     // writes visible to own wave's reads
            #pragma unroll 4
            for (int el = 0; el < 32; ++el) {
                unsigned v = U[el * 65 + lane];
                int eg = n0 + wn * 64 + ch * 32 + el;
                VtU[(((size_t)b_ * D_ + eg) * S_ + sbase) / 2 + lane] = v;
            }
            if (ch == 0) { LGKM0; SB0; }   // reads done before chunk-1 writes
        }
    }
}

// ---------------------------------------------------------------------------
// qk_pexp: per lower-tri tile pair: P = exp(Q@K^T) bf16 tile-packed, partial l.
// NEW: BK=32 ring-of-3 (48 KB -> 3 blocks/CU), counted vmcnt(4) boundary.
// XCD-swizzled: XCD r owns qt rows {r, 31-r, 8+r, 23-r} (66 blocks each).
// ---------------------------------------------------------------------------
__global__ __launch_bounds__(256, 3) void qk_pexp(
    const unsigned short* __restrict__ Q, const unsigned short* __restrict__ K,
    unsigned short* __restrict__ P, float* __restrict__ lpart)
{
    __shared__ __align__(16) unsigned short ls[3 * 8192];   // 48 KB ring
    __shared__ float sml[2][128];

    const int l = blockIdx.x, b = blockIdx.y;
    const int r = l & 7;          // xcd
    const int s = l >> 3;         // 0..65
    int qt, kt;
    if (s < r + 1)            { qt = r;      kt = s; }
    else if (s < 33)          { qt = 31 - r; kt = s - (r + 1); }
    else if (s < 42 + r)      { qt = 8 + r;  kt = s - 33; }
    else                      { qt = 23 - r; kt = s - (42 + r); }
    const int p = qt * (qt + 1) / 2 + kt;

    const int q0 = qt * 128, k0 = kt * 128;
    const int tid = threadIdx.x, lane = tid & 63, w = tid >> 6;
    const int wm = w >> 1, wn = w & 1, quad = lane >> 4, ln = lane & 15;
    const size_t base = (size_t)b * S_ * D_;

    const unsigned short* Qb = Q + base + (size_t)q0 * D_;
    const unsigned short* Kb = K + base + (size_t)k0 * D_;

#define QK_STAGE(kt_, r_)                                                         \
    {                                                                             \
        _Pragma("unroll")                                                         \
        for (int i_ = 0; i_ < 2; ++i_) {                                          \
            int g_ = tid + i_ * 256;                                              \
            int row_ = g_ >> 2;                                                   \
            int gs_ = (g_ & 3) ^ ((row_ >> 1) & 3);                               \
            gld_lds16(Qb + (size_t)row_ * D_ + (kt_) * 32 + gs_ * 8,              \
                      ls + (r_) * 8192 + g_ * 8);                                 \
            gld_lds16(Kb + (size_t)row_ * D_ + (kt_) * 32 + gs_ * 8,              \
                      ls + (r_) * 8192 + 4096 + g_ * 8);                          \
        }                                                                         \
    }

    f32x4 acc[4][4] = {};

#define QK_BODY(r_)                                                              \
    {                                                                            \
        const unsigned short* As_ = ls + (r_) * 8192;                            \
        const unsigned short* Bs_ = As_ + 4096;                                  \
        short8 a_[4], b_[4];                                                     \
        _Pragma("unroll")                                                        \
        for (int mf_ = 0; mf_ < 4; ++mf_) {                                      \
            int row_ = wm * 64 + mf_ * 16 + ln;                                  \
            int g_ = quad ^ ((row_ >> 1) & 3);                                   \
            a_[mf_] = *(const short8*)&As_[row_ * 32 + g_ * 8];                  \
        }                                                                        \
        _Pragma("unroll")                                                        \
        for (int nf_ = 0; nf_ < 4; ++nf_) {                                      \
            int row_ = wn * 64 + nf_ * 16 + ln;                                  \
            int g_ = quad ^ ((row_ >> 1) & 3);                                   \
            b_[nf_] = *(const short8*)&Bs_[row_ * 32 + g_ * 8];                  \
        }                                                                        \
        __builtin_amdgcn_s_setprio(1);                                          \
        _Pragma("unroll")                                                        \
        for (int mf_ = 0; mf_ < 4; ++mf_)                                        \
            _Pragma("unroll")                                                    \
            for (int nf_ = 0; nf_ < 4; ++nf_)                                    \
                acc[mf_][nf_] = __builtin_amdgcn_mfma_f32_16x16x32_bf16(         \
                    a_[mf_], b_[nf_], acc[mf_][nf_], 0, 0, 0);                   \
        __builtin_amdgcn_s_setprio(0);                                          \
    }

#define QK_STEP(t, r_, rn, wcode)                                                \
    {                                                                            \
        if ((wcode) == 0) QK_STAGE((t) + 2, rn)                                  \
        SB0;                                                                     \
        QK_BODY(r_)                                                              \
        LGKM0; SB0;                                                              \
        if ((wcode) == 0)      { VM4; SB0; BAR; SB0; }                           \
        else if ((wcode) == 1) { VM0; SB0; BAR; SB0; }                           \
    }

    QK_STAGE(0, 0) QK_STAGE(1, 1)
    VM4; SB0;
    BAR; SB0;

    #pragma unroll 1
    for (int tb = 0; tb < 30; tb += 3) {
        QK_STEP(tb,     0, 2, 0)
        QK_STEP(tb + 1, 1, 0, 0)
        QK_STEP(tb + 2, 2, 1, 0)
    }
    QK_STEP(30, 0, 0, 1)
    QK_STEP(31, 1, 0, 2)

#undef QK_STAGE
#undef QK_BODY
#undef QK_STEP

    const bool diag = (kt == qt);
    unsigned short* Pt = P + ((size_t)b * PAIRS_ + p) * (128 * 128);

    #pragma unroll
    for (int mf = 0; mf < 4; ++mf)
        #pragma unroll
        for (int rr = 0; rr < 4; ++rr) {
            int rowq = wm * 64 + mf * 16 + quad * 4 + rr;
            float lsum = 0.0f;
            #pragma unroll
            for (int nf = 0; nf < 4; ++nf) {
                int ckey = wn * 64 + nf * 16 + ln;
                float sc = acc[mf][nf][rr];
                float pe = (diag && ckey > rowq) ? 0.0f : __expf(fminf(sc, 60.0f));
                Pt[rowq * 128 + ckey] = f2bf(pe);
                lsum += pe;
            }
            #pragma unroll
            for (int off = 1; off < 16; off <<= 1)
                lsum += __shfl_xor(lsum, off);
            if (ln == 0) sml[wn][rowq] = lsum;
        }
    __syncthreads();

    if (tid < 128)
        lpart[((size_t)b * PAIRS_ + p) * 128 + tid] = sml[0][tid] + sml[1][tid];
}

// ---------------------------------------------------------------------------
// merge_il: il[b][q] = 1 / sum_kt l_t
// ---------------------------------------------------------------------------
__global__ __launch_bounds__(128) void merge_il(const float* __restrict__ lpart,
                                                float* __restrict__ il) {
    const int qt = blockIdx.x, b = blockIdx.y;
    const int row = threadIdx.x;
    const int pbase = qt * (qt + 1) / 2;
    float l = 0.0f;
    for (int kt = 0; kt <= qt; ++kt)
        l += lpart[((size_t)b * PAIRS_ + pbase + kt) * 128 + row];
    il[(size_t)b * S_ + qt * 128 + row] = 1.0f / l;
}

// ---------------------------------------------------------------------------
// pv_gemm: O = (P @ V) * il.  128x128 tiles, paired q-tiles (exact balance).
// NEW: BK=32 ring-of-3 (48 KB), counted vmcnt(4). XCD-sibling remap kept
// (all 8 d-slices of a (b,pair) on one XCD -> P fetched once per XCD).
// ---------------------------------------------------------------------------
__global__ __launch_bounds__(256, 3) void pv_gemm(
    const unsigned short* __restrict__ P, const unsigned short* __restrict__ Vt,
    const float* __restrict__ il, float* __restrict__ O)
{
    __shared__ __align__(16) unsigned short ls[3 * 8192];   // 48 KB ring

    const int bid = blockIdx.x;                      // 0..511
    const int u  = (bid & 7) | ((bid >> 6) << 3);    // 0..63  (b*16+pair)
    const int dt = (bid >> 3) & 7;                   // 0..7   d-slice
    const int pair = u & 15;
    const int b = u >> 4;
    const int d0 = dt * 128;
    const int tid = threadIdx.x, lane = tid & 63, w = tid >> 6;
    const int wm = w >> 1, wn = w & 1, quad = lane >> 4, ln = lane & 15;

    const unsigned short* Vtb = Vt + ((size_t)b * D_ + d0) * S_;

#define PV_STAGE(c_, r_)                                                          \
    {                                                                             \
        const unsigned short* Pt_ = Pbase + (size_t)((c_) >> 2) * (128 * 128);    \
        _Pragma("unroll")                                                         \
        for (int i_ = 0; i_ < 2; ++i_) {                                          \
            int g_ = tid + i_ * 256;                                              \
            int row_ = g_ >> 2;                                                   \
            int gs_ = (g_ & 3) ^ ((row_ >> 1) & 3);                               \
            gld_lds16(Pt_ + (size_t)row_ * 128 + ((c_) & 3) * 32 + gs_ * 8,       \
                      ls + (r_) * 8192 + g_ * 8);                                 \
            gld_lds16(Vtb + (size_t)row_ * S_ + (c_) * 32 + gs_ * 8,              \
                      ls + (r_) * 8192 + 4096 + g_ * 8);                          \
        }                                                                         \
    }

#define PV_BODY(r_)                                                              \
    {                                                                            \
        const unsigned short* As_ = ls + (r_) * 8192;                            \
        const unsigned short* Bs_ = As_ + 4096;                                  \
        short8 a_[4], b_[4];                                                     \
        _Pragma("unroll")                                                        \
        for (int mf_ = 0; mf_ < 4; ++mf_) {                                      \
            int row_ = wm * 64 + mf_ * 16 + ln;                                  \
            int g_ = quad ^ ((row_ >> 1) & 3);                                   \
            a_[mf_] = *(const short8*)&As_[row_ * 32 + g_ * 8];                  \
        }                                                                        \
        _Pragma("unroll")                                                        \
        for (int nf_ = 0; nf_ < 4; ++nf_) {                                      \
            int row_ = wn * 64 + nf_ * 16 + ln;                                  \
            int g_ = quad ^ ((row_ >> 1) & 3);                                   \
            b_[nf_] = *(const short8*)&Bs_[row_ * 32 + g_ * 8];                  \
        }                                                                        \
        __builtin_amdgcn_s_setprio(1);                                          \
        _Pragma("unroll")                                                        \
        for (int mf_ = 0; mf_ < 4; ++mf_)                                        \
            _Pragma("unroll")                                                    \
            for (int nf_ = 0; nf_ < 4; ++nf_)                                    \
                acc[mf_][nf_] = __builtin_amdgcn_mfma_f32_16x16x32_bf16(         \
                    a_[mf_], b_[nf_], acc[mf_][nf_], 0, 0, 0);                   \
        __builtin_amdgcn_s_setprio(0);                                          \
    }

    #pragma unroll 1
    for (int half = 0; half < 2; ++half) {
        const int qt = half ? pair : (31 - pair);   // heavy first
        const int q0 = qt * 128;
        const int pbase = qt * (qt + 1) / 2;
        const int nst = 4 * (qt + 1);
        const unsigned short* Pbase = P + ((size_t)b * PAIRS_ + pbase) * (128 * 128);

        f32x4 acc[4][4] = {};

        if (half) { BAR; SB0; }      // protect ring reuse across halves
        PV_STAGE(0, 0) PV_STAGE(1, 1)
        VM4; SB0;
        BAR; SB0;

        #pragma unroll 1
        for (int t = 0; t < nst; ++t) {
            const int r_ = t % 3;
            if (t + 2 < nst) { const int rn_ = (t + 2) % 3; PV_STAGE(t + 2, rn_) }
            SB0;
            PV_BODY(r_)
            LGKM0; SB0;
            if (t + 2 < nst)      { VM4; SB0; }
            else if (t + 1 < nst) { VM0; SB0; }
            if (t + 1 < nst) { BAR; SB0; }
        }

        #pragma unroll
        for (int mf = 0; mf < 4; ++mf) {
            float ilv[4];
            #pragma unroll
            for (int rr = 0; rr < 4; ++rr)
                ilv[rr] = il[(size_t)b * S_ + q0 + wm * 64 + mf * 16 + quad * 4 + rr];
            #pragma unroll
            for (int nf = 0; nf < 4; ++nf)
                #pragma unroll
                for (int rr = 0; rr < 4; ++rr) {
                    int rowq = q0 + wm * 64 + mf * 16 + quad * 4 + rr;
                    int col = d0 + wn * 64 + nf * 16 + ln;
                    O[((size_t)b * S_ + rowq) * D_ + col] = acc[mf][nf][rr] * ilv[rr];
                }
        }
    }
#undef PV_STAGE
#undef PV_BODY
}

extern "C" void kernel_launch(void* const* d_in, const int* in_sizes, int n_in,
                              void* d_out, int out_size, void* d_ws, size_t ws_size,
                              hipStream_t stream) {
    const float* x  = (const float*)d_in[0];
    const float* Wq = (const float*)d_in[1];
    const float* Wk = (const float*)d_in[2];
    const float* Wv = (const float*)d_in[3];

    const size_t nQ = (size_t)B_ * S_ * D_;
    const size_t nP = (size_t)B_ * PAIRS_ * 128 * 128;

    unsigned short* P  = (unsigned short*)d_ws;
    unsigned short* xb = P;                       // alias: dead before P written
    unsigned short* Q  = P + nP;
    unsigned short* K  = Q + nQ;
    unsigned short* Vt = K + nQ;
    unsigned short* Wt = Vt + nQ;
    float* lpart = (float*)(Wt + (size_t)3 * D_ * D_);
    float* il    = lpart + (size_t)B_ * PAIRS_ * 128;
    float* O = (float*)d_out;

    hipLaunchKernelGGL(prep_x, dim3(8192), dim3(256), 0, stream, x, xb);
    hipLaunchKernelGGL(prep_w, dim3(16, 16, 3), dim3(256), 0, stream, Wq, Wk, Wv, Wt);
    hipLaunchKernelGGL(qkv_gemm, dim3(256, 1, 3), dim3(512), 0, stream, xb, Wt, Q, K, Vt);
    hipLaunchKernelGGL(qk_pexp, dim3(PAIRS_, B_), dim3(256), 0, stream, Q, K, P, lpart);
    hipLaunchKernelGGL(merge_il, dim3(NT_, B_), dim3(128), 0, stream, lpart, il);
    hipLaunchKernelGGL(pv_gemm, dim3(512), dim3(256), 0, stream, P, Vt, il, O);
}

// Round 6
// 405.217 us; speedup vs baseline: 1.1300x; 1.0457x over previous
//
#include <hip/hip_runtime.h>
#include <hip/hip_bf16.h>

#define B_ 4
#define S_ 4096
#define D_ 1024
#define NT_ 32        // S_/128
#define PAIRS_ 528    // NT_*(NT_+1)/2 lower-triangle tile pairs

typedef __attribute__((ext_vector_type(8))) short short8;
typedef __attribute__((ext_vector_type(4))) float f32x4;

__device__ __forceinline__ unsigned short f2bf(float f) {
    union { float f; unsigned u; } v; v.f = f;
    unsigned u = v.u;
    return (unsigned short)((u + 0x7fffu + ((u >> 16) & 1u)) >> 16);
}

// async global->LDS, 16B per lane. LDS dst is wave-uniform base + lane*16.
__device__ __forceinline__ void gld_lds16(const unsigned short* g, unsigned short* l) {
    __builtin_amdgcn_global_load_lds((const __attribute__((address_space(1))) void*)g,
                                     (__attribute__((address_space(3))) void*)l, 16, 0, 0);
}

#define LGKM0 asm volatile("s_waitcnt lgkmcnt(0)" ::: "memory")
#define VM0   asm volatile("s_waitcnt vmcnt(0)" ::: "memory")
#define VM4   asm volatile("s_waitcnt vmcnt(4)" ::: "memory")
#define VM6   asm volatile("s_waitcnt vmcnt(6)" ::: "memory")
#define BAR   __builtin_amdgcn_s_barrier()
#define SB0   __builtin_amdgcn_sched_barrier(0)

// ---------------------------------------------------------------------------
// prep_x: fp32 x -> bf16 xb
// ---------------------------------------------------------------------------
__global__ __launch_bounds__(256) void prep_x(const float* __restrict__ x,
                                              unsigned short* __restrict__ xb) {
    size_t i = ((size_t)blockIdx.x * 256 + threadIdx.x) * 8;
    float4 a = *(const float4*)&x[i];
    float4 b = *(const float4*)&x[i + 4];
    unsigned u0 = (unsigned)f2bf(a.x) | ((unsigned)f2bf(a.y) << 16);
    unsigned u1 = (unsigned)f2bf(a.z) | ((unsigned)f2bf(a.w) << 16);
    unsigned u2 = (unsigned)f2bf(b.x) | ((unsigned)f2bf(b.y) << 16);
    unsigned u3 = (unsigned)f2bf(b.z) | ((unsigned)f2bf(b.w) << 16);
    uint4 val; val.x = u0; val.y = u1; val.z = u2; val.w = u3;
    *(uint4*)&xb[i] = val;
}

// ---------------------------------------------------------------------------
// prep_w: W[k][n] fp32 -> Wt[n][k] bf16
// ---------------------------------------------------------------------------
__global__ __launch_bounds__(256) void prep_w(const float* __restrict__ Wq,
                                              const float* __restrict__ Wk,
                                              const float* __restrict__ Wv,
                                              unsigned short* __restrict__ Wt) {
    __shared__ float ls[64 * 65];
    const int z = blockIdx.z;
    const float* __restrict__ W = (z == 0) ? Wq : (z == 1) ? Wk : Wv;
    unsigned short* __restrict__ Wtz = Wt + (size_t)z * D_ * D_;
    const int k0 = blockIdx.y * 64, n0 = blockIdx.x * 64;
    const int tid = threadIdx.x;
    #pragma unroll
    for (int i = 0; i < 16; ++i) {
        int lin = i * 256 + tid, r = lin >> 6, c = lin & 63;
        ls[r * 65 + c] = W[(size_t)(k0 + r) * D_ + n0 + c];
    }
    __syncthreads();
    #pragma unroll
    for (int i = 0; i < 16; ++i) {
        int lin = i * 256 + tid, r = lin >> 6, c = lin & 63;
        Wtz[(size_t)(n0 + r) * D_ + k0 + c] = f2bf(ls[c * 65 + r]);
    }
}

// ---------------------------------------------------------------------------
// qkv_gemm: Y = xb @ Wt_z^T.  256x256 tile, 8 waves (2x4).
// BK=32 ring-of-3 LDS buffers (96 KB), stage 2 steps ahead, counted
// boundary wait vmcnt(4). BK=32 swizzle: granule ^= (row>>1)&3, inverse on
// global source + forward on ds_read. z==2 writes Vt directly (LDS transpose).
// ---------------------------------------------------------------------------
__global__ __launch_bounds__(512, 2) void qkv_gemm(
    const unsigned short* __restrict__ xb, const unsigned short* __restrict__ Wt,
    unsigned short* __restrict__ Q, unsigned short* __restrict__ K,
    unsigned short* __restrict__ Vt)
{
    __shared__ __align__(16) unsigned short ls[3 * 16384];   // 96 KiB ring

    const int z = blockIdx.z;
    const float scale = (z == 0) ? 0.03125f : 1.0f;

    const int lin = blockIdx.x;                       // 0..255
    const int wg = (lin & 7) * 32 + (lin >> 3);       // XCD-contiguous
    const int m0 = (wg >> 2) * 256, n0 = (wg & 3) * 256;

    const int tid = threadIdx.x, lane = tid & 63, w = tid >> 6;
    const int wm = w >> 2, wn = w & 3;                // 2 x 4 wave grid
    const int quad = lane >> 4, ln = lane & 15;

    const unsigned short* Ab = xb + (size_t)m0 * D_;
    const unsigned short* Bb = Wt + (size_t)z * D_ * D_ + (size_t)n0 * D_;

#define QKV_STAGE(kt, r)                                                          \
    {                                                                             \
        _Pragma("unroll")                                                         \
        for (int i_ = 0; i_ < 2; ++i_) {                                          \
            int g_ = tid + i_ * 512;                                              \
            int row_ = g_ >> 2;                                                   \
            int gs_ = (g_ & 3) ^ ((row_ >> 1) & 3);                               \
            gld_lds16(Ab + (size_t)row_ * D_ + (kt) * 32 + gs_ * 8,               \
                      ls + (r) * 16384 + g_ * 8);                                 \
            gld_lds16(Bb + (size_t)row_ * D_ + (kt) * 32 + gs_ * 8,               \
                      ls + (r) * 16384 + 8192 + g_ * 8);                          \
        }                                                                         \
    }

    f32x4 acc[8][4] = {};

#define QKV_BODY(r)                                                              \
    {                                                                            \
        const unsigned short* As_ = ls + (r) * 16384;                            \
        const unsigned short* Bs_ = As_ + 8192;                                  \
        short8 a_[8], b_[4];                                                     \
        _Pragma("unroll")                                                        \
        for (int mf_ = 0; mf_ < 8; ++mf_) {                                      \
            int row_ = wm * 128 + mf_ * 16 + ln;                                 \
            int g_ = quad ^ ((row_ >> 1) & 3);                                   \
            a_[mf_] = *(const short8*)&As_[row_ * 32 + g_ * 8];                  \
        }                                                                        \
        _Pragma("unroll")                                                        \
        for (int nf_ = 0; nf_ < 4; ++nf_) {                                      \
            int row_ = wn * 64 + nf_ * 16 + ln;                                  \
            int g_ = quad ^ ((row_ >> 1) & 3);                                   \
            b_[nf_] = *(const short8*)&Bs_[row_ * 32 + g_ * 8];                  \
        }                                                                        \
        __builtin_amdgcn_s_setprio(1);                                          \
        _Pragma("unroll")                                                        \
        for (int mf_ = 0; mf_ < 8; ++mf_)                                        \
            _Pragma("unroll")                                                    \
            for (int nf_ = 0; nf_ < 4; ++nf_)                                    \
                acc[mf_][nf_] = __builtin_amdgcn_mfma_f32_16x16x32_bf16(         \
                    a_[mf_], b_[nf_], acc[mf_][nf_], 0, 0, 0);                   \
        __builtin_amdgcn_s_setprio(0);                                          \
    }

#define QKV_STEP(t, r, rn, wcode)                                                \
    {                                                                            \
        if ((wcode) == 0) QKV_STAGE((t) + 2, rn)                                 \
        SB0;                                                                     \
        QKV_BODY(r)                                                              \
        LGKM0; SB0;                                                              \
        if ((wcode) == 0)      { VM4; SB0; BAR; SB0; }                           \
        else if ((wcode) == 1) { VM0; SB0; BAR; SB0; }                           \
    }

    QKV_STAGE(0, 0) QKV_STAGE(1, 1)
    VM4; SB0;
    BAR; SB0;

    #pragma unroll 1
    for (int tb = 0; tb < 30; tb += 3) {
        QKV_STEP(tb,     0, 2, 0)
        QKV_STEP(tb + 1, 1, 0, 0)
        QKV_STEP(tb + 2, 2, 1, 0)
    }
    QKV_STEP(30, 0, 0, 1)
    QKV_STEP(31, 1, 0, 2)

#undef QKV_STAGE
#undef QKV_BODY
#undef QKV_STEP

    if (z != 2) {
        unsigned short* __restrict__ Y = (z == 0) ? Q : K;
        #pragma unroll
        for (int mf = 0; mf < 8; ++mf)
            #pragma unroll
            for (int nf = 0; nf < 4; ++nf)
                #pragma unroll
                for (int rr = 0; rr < 4; ++rr) {
                    int row = m0 + wm * 128 + mf * 16 + quad * 4 + rr;
                    int col = n0 + wn * 64 + nf * 16 + ln;
                    Y[(size_t)row * D_ + col] = f2bf(acc[mf][nf][rr] * scale);
                }
    } else {
        // transposed store: Vt[b][e][s].  Per-wave LDS transpose, packed u32.
        BAR;                                   // all waves done with ring reads
        unsigned int* U = (unsigned int*)ls + w * 2080;     // [32 e][65 u32]
        const int b_ = m0 >> 12;                            // batch
        const int sbase = (m0 & 4095) + wm * 128;           // s within batch
        unsigned int* VtU = (unsigned int*)Vt;
        #pragma unroll
        for (int ch = 0; ch < 2; ++ch) {
            #pragma unroll
            for (int nfl = 0; nfl < 2; ++nfl) {
                int nf = ch * 2 + nfl;
                int el = nfl * 16 + ln;
                #pragma unroll
                for (int mf = 0; mf < 8; ++mf)
                    #pragma unroll
                    for (int pr = 0; pr < 2; ++pr) {
                        unsigned lo = f2bf(acc[mf][nf][2 * pr]);
                        unsigned hi = f2bf(acc[mf][nf][2 * pr + 1]);
                        U[el * 65 + mf * 8 + quad * 2 + pr] = lo | (hi << 16);
                    }
            }
            LGKM0; SB0;     // writes visible to own wave's reads
            #pragma unroll 4
            for (int el = 0; el < 32; ++el) {
                unsigned v = U[el * 65 + lane];
                int eg = n0 + wn * 64 + ch * 32 + el;
                VtU[(((size_t)b_ * D_ + eg) * S_ + sbase) / 2 + lane] = v;
            }
            if (ch == 0) { LGKM0; SB0; }   // reads done before chunk-1 writes
        }
    }
}

// ---------------------------------------------------------------------------
// qk_pexp: P = exp(Q@K^T) bf16 tile-packed + partial row sums.
// NEW: kt-PAIRED blocks.  A paired block covers 128q x 256k (kt = 2j, 2j+1,
// requires qt >= 2j+1): Q staged ONCE for two K tiles, 4 waves in 2x2 ->
// wave-tile 64x128 (12 ds_reads per 32 MFMA, 1.5x better than 64x64).
// Even-qt diagonal tiles (kt==qt) run a solo 128x128 path (half-masked).
// Per XCD per batch: exactly 32 pairs + 2 solos (qt groups {r,31-r,8+r,23-r}).
// BK=32 ring-of-3 (72 KB -> 2 blocks/CU), counted vmcnt(6)/(4) boundary.
// ---------------------------------------------------------------------------
__global__ __launch_bounds__(256, 2) void qk_pexp(
    const unsigned short* __restrict__ Q, const unsigned short* __restrict__ K,
    unsigned short* __restrict__ P, float* __restrict__ lpart)
{
    __shared__ __align__(16) unsigned short ls[3 * 12288];   // 72 KB ring
    __shared__ float sml[2][128];

    const int l = blockIdx.x, b = blockIdx.y;
    const int r = l & 7;          // xcd
    const int s = l >> 3;         // 0..33: 0-31 pairs, 32-33 solo diagonals
    const size_t base = (size_t)b * S_ * D_;
    const int tid = threadIdx.x, lane = tid & 63, w = tid >> 6;
    const int wm = w >> 1, wn = w & 1, quad = lane >> 4, ln = lane & 15;

    if (s < 32) {
        // ---------------- paired path: 128q x 256k ----------------
        const int qts0 = r, qts1 = 31 - r, qts2 = 8 + r, qts3 = 23 - r;
        int qt = -1, j = 0, rem = s;
        {
            int np;
            np = (qts0 + 1) >> 1; if (rem < np) { qt = qts0; j = rem; } rem -= np;
            np = (qts1 + 1) >> 1; if (qt < 0 && rem < np) { qt = qts1; j = rem; } if (qt < 0) rem -= np;
            np = (qts2 + 1) >> 1; if (qt < 0 && rem < np) { qt = qts2; j = rem; } if (qt < 0) rem -= np;
            if (qt < 0) { qt = qts3; j = rem; }
        }
        const int q0 = qt * 128;
        const int p0 = qt * (qt + 1) / 2 + 2 * j;
        const unsigned short* Qb  = Q + base + (size_t)q0 * D_;
        const unsigned short* Kb2 = K + base + (size_t)(j * 256) * D_;

#define QP_STAGE(c_, r_)                                                          \
    {                                                                             \
        _Pragma("unroll")                                                         \
        for (int i_ = 0; i_ < 2; ++i_) {                                          \
            int g_ = tid + i_ * 256;                                              \
            int row_ = g_ >> 2;                                                   \
            int gs_ = (g_ & 3) ^ ((row_ >> 1) & 3);                               \
            gld_lds16(Qb + (size_t)row_ * D_ + (c_) * 32 + gs_ * 8,               \
                      ls + (r_) * 12288 + g_ * 8);                                \
        }                                                                         \
        _Pragma("unroll")                                                         \
        for (int i_ = 0; i_ < 4; ++i_) {                                          \
            int g_ = tid + i_ * 256;                                              \
            int row_ = g_ >> 2;                                                   \
            int gs_ = (g_ & 3) ^ ((row_ >> 1) & 3);                               \
            gld_lds16(Kb2 + (size_t)row_ * D_ + (c_) * 32 + gs_ * 8,              \
                      ls + (r_) * 12288 + 4096 + g_ * 8);                         \
        }                                                                         \
    }

        f32x4 acc[4][8] = {};

#define QP_BODY(r_)                                                              \
    {                                                                            \
        const unsigned short* As_ = ls + (r_) * 12288;                           \
        const unsigned short* Bs_ = As_ + 4096;                                  \
        short8 a_[4], b_[8];                                                     \
        _Pragma("unroll")                                                        \
        for (int mf_ = 0; mf_ < 4; ++mf_) {                                      \
            int row_ = wm * 64 + mf_ * 16 + ln;                                  \
            int g_ = quad ^ ((row_ >> 1) & 3);                                   \
            a_[mf_] = *(const short8*)&As_[row_ * 32 + g_ * 8];                  \
        }                                                                        \
        _Pragma("unroll")                                                        \
        for (int nf_ = 0; nf_ < 8; ++nf_) {                                      \
            int row_ = wn * 128 + nf_ * 16 + ln;                                 \
            int g_ = quad ^ ((row_ >> 1) & 3);                                   \
            b_[nf_] = *(const short8*)&Bs_[row_ * 32 + g_ * 8];                  \
        }                                                                        \
        __builtin_amdgcn_s_setprio(1);                                          \
        _Pragma("unroll")                                                        \
        for (int mf_ = 0; mf_ < 4; ++mf_)                                        \
            _Pragma("unroll")                                                    \
            for (int nf_ = 0; nf_ < 8; ++nf_)                                    \
                acc[mf_][nf_] = __builtin_amdgcn_mfma_f32_16x16x32_bf16(         \
                    a_[mf_], b_[nf_], acc[mf_][nf_], 0, 0, 0);                   \
        __builtin_amdgcn_s_setprio(0);                                          \
    }

#define QP_STEP(t, r_, rn, wcode)                                                \
    {                                                                            \
        if ((wcode) == 0) QP_STAGE((t) + 2, rn)                                  \
        SB0;                                                                     \
        QP_BODY(r_)                                                              \
        LGKM0; SB0;                                                              \
        if ((wcode) == 0)      { VM6; SB0; BAR; SB0; }                           \
        else if ((wcode) == 1) { VM0; SB0; BAR; SB0; }                           \
    }

        QP_STAGE(0, 0) QP_STAGE(1, 1)
        VM6; SB0;
        BAR; SB0;

        #pragma unroll 1
        for (int tb = 0; tb < 30; tb += 3) {
            QP_STEP(tb,     0, 2, 0)
            QP_STEP(tb + 1, 1, 0, 0)
            QP_STEP(tb + 2, 2, 1, 0)
        }
        QP_STEP(30, 0, 0, 1)
        QP_STEP(31, 1, 0, 2)

#undef QP_STAGE
#undef QP_BODY
#undef QP_STEP

        // epilogue: exp + P write (wave wn owns tile p0+wn) + partial sums
        const bool mt = (2 * j + 1 == qt) && (wn == 1);   // diagonal tile in pair
        unsigned short* Pt = P + ((size_t)b * PAIRS_ + p0 + wn) * (128 * 128);
        #pragma unroll
        for (int mf = 0; mf < 4; ++mf)
            #pragma unroll
            for (int rr = 0; rr < 4; ++rr) {
                int rowq = wm * 64 + mf * 16 + quad * 4 + rr;
                float lsum = 0.0f;
                #pragma unroll
                for (int nf = 0; nf < 8; ++nf) {
                    int ckey = nf * 16 + ln;
                    float sc = acc[mf][nf][rr];
                    float pe = (mt && ckey > rowq) ? 0.0f : __expf(fminf(sc, 60.0f));
                    Pt[rowq * 128 + ckey] = f2bf(pe);
                    lsum += pe;
                }
                #pragma unroll
                for (int off = 1; off < 16; off <<= 1)
                    lsum += __shfl_xor(lsum, off);
                if (ln == 0) sml[wn][rowq] = lsum;
            }
        __syncthreads();
        if (tid < 128) {
            lpart[((size_t)b * PAIRS_ + p0) * 128 + tid]     = sml[0][tid];
            lpart[((size_t)b * PAIRS_ + p0 + 1) * 128 + tid] = sml[1][tid];
        }
    } else {
        // ---------------- solo path: even-qt diagonal 128x128 ----------------
        const int qt = (r & 1) ? ((s == 32) ? 31 - r : 23 - r)
                               : ((s == 32) ? r : 8 + r);
        const int q0 = qt * 128;
        const int p = qt * (qt + 1) / 2 + qt;
        const unsigned short* Qb = Q + base + (size_t)q0 * D_;
        const unsigned short* Kb = K + base + (size_t)q0 * D_;

#define QS_STAGE(c_, r_)                                                          \
    {                                                                             \
        _Pragma("unroll")                                                         \
        for (int i_ = 0; i_ < 2; ++i_) {                                          \
            int g_ = tid + i_ * 256;                                              \
            int row_ = g_ >> 2;                                                   \
            int gs_ = (g_ & 3) ^ ((row_ >> 1) & 3);                               \
            gld_lds16(Qb + (size_t)row_ * D_ + (c_) * 32 + gs_ * 8,               \
                      ls + (r_) * 12288 + g_ * 8);                                \
            gld_lds16(Kb + (size_t)row_ * D_ + (c_) * 32 + gs_ * 8,               \
                      ls + (r_) * 12288 + 4096 + g_ * 8);                         \
        }                                                                         \
    }

        f32x4 acc[4][4] = {};

#define QS_BODY(r_)                                                              \
    {                                                                            \
        const unsigned short* As_ = ls + (r_) * 12288;                           \
        const unsigned short* Bs_ = As_ + 4096;                                  \
        short8 a_[4], b_[4];                                                     \
        _Pragma("unroll")                                                        \
        for (int mf_ = 0; mf_ < 4; ++mf_) {                                      \
            int row_ = wm * 64 + mf_ * 16 + ln;                                  \
            int g_ = quad ^ ((row_ >> 1) & 3);                                   \
            a_[mf_] = *(const short8*)&As_[row_ * 32 + g_ * 8];                  \
        }                                                                        \
        _Pragma("unroll")                                                        \
        for (int nf_ = 0; nf_ < 4; ++nf_) {                                      \
            int row_ = wn * 64 + nf_ * 16 + ln;                                  \
            int g_ = quad ^ ((row_ >> 1) & 3);                                   \
            b_[nf_] = *(const short8*)&Bs_[row_ * 32 + g_ * 8];                  \
        }                                                                        \
        __builtin_amdgcn_s_setprio(1);                                          \
        _Pragma("unroll")                                                        \
        for (int mf_ = 0; mf_ < 4; ++mf_)                                        \
            _Pragma("unroll")                                                    \
            for (int nf_ = 0; nf_ < 4; ++nf_)                                    \
                acc[mf_][nf_] = __builtin_amdgcn_mfma_f32_16x16x32_bf16(         \
                    a_[mf_], b_[nf_], acc[mf_][nf_], 0, 0, 0);                   \
        __builtin_amdgcn_s_setprio(0);                                          \
    }

#define QS_STEP(t, r_, rn, wcode)                                                \
    {                                                                            \
        if ((wcode) == 0) QS_STAGE((t) + 2, rn)                                  \
        SB0;                                                                     \
        QS_BODY(r_)                                                              \
        LGKM0; SB0;                                                              \
        if ((wcode) == 0)      { VM4; SB0; BAR; SB0; }                           \
        else if ((wcode) == 1) { VM0; SB0; BAR; SB0; }                           \
    }

        QS_STAGE(0, 0) QS_STAGE(1, 1)
        VM4; SB0;
        BAR; SB0;

        #pragma unroll 1
        for (int tb = 0; tb < 30; tb += 3) {
            QS_STEP(tb,     0, 2, 0)
            QS_STEP(tb + 1, 1, 0, 0)
            QS_STEP(tb + 2, 2, 1, 0)
        }
        QS_STEP(30, 0, 0, 1)
        QS_STEP(31, 1, 0, 2)

#undef QS_STAGE
#undef QS_BODY
#undef QS_STEP

        unsigned short* Pt = P + ((size_t)b * PAIRS_ + p) * (128 * 128);
        #pragma unroll
        for (int mf = 0; mf < 4; ++mf)
            #pragma unroll
            for (int rr = 0; rr < 4; ++rr) {
                int rowq = wm * 64 + mf * 16 + quad * 4 + rr;
                float lsum = 0.0f;
                #pragma unroll
                for (int nf = 0; nf < 4; ++nf) {
                    int ckey = wn * 64 + nf * 16 + ln;
                    float sc = acc[mf][nf][rr];
                    float pe = (ckey > rowq) ? 0.0f : __expf(fminf(sc, 60.0f));
                    Pt[rowq * 128 + ckey] = f2bf(pe);
                    lsum += pe;
                }
                #pragma unroll
                for (int off = 1; off < 16; off <<= 1)
                    lsum += __shfl_xor(lsum, off);
                if (ln == 0) sml[wn][rowq] = lsum;
            }
        __syncthreads();
        if (tid < 128)
            lpart[((size_t)b * PAIRS_ + p) * 128 + tid] = sml[0][tid] + sml[1][tid];
    }
}

// ---------------------------------------------------------------------------
// merge_il: il[b][q] = 1 / sum_kt l_t
// ---------------------------------------------------------------------------
__global__ __launch_bounds__(128) void merge_il(const float* __restrict__ lpart,
                                                float* __restrict__ il) {
    const int qt = blockIdx.x, b = blockIdx.y;
    const int row = threadIdx.x;
    const int pbase = qt * (qt + 1) / 2;
    float l = 0.0f;
    for (int kt = 0; kt <= qt; ++kt)
        l += lpart[((size_t)b * PAIRS_ + pbase + kt) * 128 + row];
    il[(size_t)b * S_ + qt * 128 + row] = 1.0f / l;
}

// ---------------------------------------------------------------------------
// pv_gemm: O = (P @ V) * il.  128x128 tiles, paired q-tiles (exact balance).
// BK=32 ring-of-3 (48 KB), counted vmcnt(4). XCD-sibling remap (all 8
// d-slices of a (b,pair) on one XCD -> P fetched once per XCD).
// ---------------------------------------------------------------------------
__global__ __launch_bounds__(256, 3) void pv_gemm(
    const unsigned short* __restrict__ P, const unsigned short* __restrict__ Vt,
    const float* __restrict__ il, float* __restrict__ O)
{
    __shared__ __align__(16) unsigned short ls[3 * 8192];   // 48 KB ring

    const int bid = blockIdx.x;                      // 0..511
    const int u  = (bid & 7) | ((bid >> 6) << 3);    // 0..63  (b*16+pair)
    const int dt = (bid >> 3) & 7;                   // 0..7   d-slice
    const int pair = u & 15;
    const int b = u >> 4;
    const int d0 = dt * 128;
    const int tid = threadIdx.x, lane = tid & 63, w = tid >> 6;
    const int wm = w >> 1, wn = w & 1, quad = lane >> 4, ln = lane & 15;

    const unsigned short* Vtb = Vt + ((size_t)b * D_ + d0) * S_;

#define PV_STAGE(c_, r_)                                                          \
    {                                                                             \
        const unsigned short* Pt_ = Pbase + (size_t)((c_) >> 2) * (128 * 128);    \
        _Pragma("unroll")                                                         \
        for (int i_ = 0; i_ < 2; ++i_) {                                          \
            int g_ = tid + i_ * 256;                                              \
            int row_ = g_ >> 2;                                                   \
            int gs_ = (g_ & 3) ^ ((row_ >> 1) & 3);                               \
            gld_lds16(Pt_ + (size_t)row_ * 128 + ((c_) & 3) * 32 + gs_ * 8,       \
                      ls + (r_) * 8192 + g_ * 8);                                 \
            gld_lds16(Vtb + (size_t)row_ * S_ + (c_) * 32 + gs_ * 8,              \
                      ls + (r_) * 8192 + 4096 + g_ * 8);                          \
        }                                                                         \
    }

#define PV_BODY(r_)                                                              \
    {                                                                            \
        const unsigned short* As_ = ls + (r_) * 8192;                            \
        const unsigned short* Bs_ = As_ + 4096;                                  \
        short8 a_[4], b_[4];                                                     \
        _Pragma("unroll")                                                        \
        for (int mf_ = 0; mf_ < 4; ++mf_) {                                      \
            int row_ = wm * 64 + mf_ * 16 + ln;                                  \
            int g_ = quad ^ ((row_ >> 1) & 3);                                   \
            a_[mf_] = *(const short8*)&As_[row_ * 32 + g_ * 8];                  \
        }                                                                        \
        _Pragma("unroll")                                                        \
        for (int nf_ = 0; nf_ < 4; ++nf_) {                                      \
            int row_ = wn * 64 + nf_ * 16 + ln;                                  \
            int g_ = quad ^ ((row_ >> 1) & 3);                                   \
            b_[nf_] = *(const short8*)&Bs_[row_ * 32 + g_ * 8];                  \
        }                                                                        \
        __builtin_amdgcn_s_setprio(1);                                          \
        _Pragma("unroll")                                                        \
        for (int mf_ = 0; mf_ < 4; ++mf_)                                        \
            _Pragma("unroll")                                                    \
            for (int nf_ = 0; nf_ < 4; ++nf_)                                    \
                acc[mf_][nf_] = __builtin_amdgcn_mfma_f32_16x16x32_bf16(         \
                    a_[mf_], b_[nf_], acc[mf_][nf_], 0, 0, 0);                   \
        __builtin_amdgcn_s_setprio(0);                                          \
    }

    #pragma unroll 1
    for (int half = 0; half < 2; ++half) {
        const int qt = half ? pair : (31 - pair);   // heavy first
        const int q0 = qt * 128;
        const int pbase = qt * (qt + 1) / 2;
        const int nst = 4 * (qt + 1);
        const unsigned short* Pbase = P + ((size_t)b * PAIRS_ + pbase) * (128 * 128);

        f32x4 acc[4][4] = {};

        if (half) { BAR; SB0; }      // protect ring reuse across halves
        PV_STAGE(0, 0) PV_STAGE(1, 1)
        VM4; SB0;
        BAR; SB0;

        #pragma unroll 1
        for (int t = 0; t < nst; ++t) {
            const int r_ = t % 3;
            if (t + 2 < nst) { const int rn_ = (t + 2) % 3; PV_STAGE(t + 2, rn_) }
            SB0;
            PV_BODY(r_)
            LGKM0; SB0;
            if (t + 2 < nst)      { VM4; SB0; }
            else if (t + 1 < nst) { VM0; SB0; }
            if (t + 1 < nst) { BAR; SB0; }
        }

        #pragma unroll
        for (int mf = 0; mf < 4; ++mf) {
            float ilv[4];
            #pragma unroll
            for (int rr = 0; rr < 4; ++rr)
                ilv[rr] = il[(size_t)b * S_ + q0 + wm * 64 + mf * 16 + quad * 4 + rr];
            #pragma unroll
            for (int nf = 0; nf < 4; ++nf)
                #pragma unroll
                for (int rr = 0; rr < 4; ++rr) {
                    int rowq = q0 + wm * 64 + mf * 16 + quad * 4 + rr;
                    int col = d0 + wn * 64 + nf * 16 + ln;
                    O[((size_t)b * S_ + rowq) * D_ + col] = acc[mf][nf][rr] * ilv[rr];
                }
        }
    }
#undef PV_STAGE
#undef PV_BODY
}

extern "C" void kernel_launch(void* const* d_in, const int* in_sizes, int n_in,
                              void* d_out, int out_size, void* d_ws, size_t ws_size,
                              hipStream_t stream) {
    const float* x  = (const float*)d_in[0];
    const float* Wq = (const float*)d_in[1];
    const float* Wk = (const float*)d_in[2];
    const float* Wv = (const float*)d_in[3];

    const size_t nQ = (size_t)B_ * S_ * D_;
    const size_t nP = (size_t)B_ * PAIRS_ * 128 * 128;

    unsigned short* P  = (unsigned short*)d_ws;
    unsigned short* xb = P;                       // alias: dead before P written
    unsigned short* Q  = P + nP;
    unsigned short* K  = Q + nQ;
    unsigned short* Vt = K + nQ;
    unsigned short* Wt = Vt + nQ;
    float* lpart = (float*)(Wt + (size_t)3 * D_ * D_);
    float* il    = lpart + (size_t)B_ * PAIRS_ * 128;
    float* O = (float*)d_out;

    hipLaunchKernelGGL(prep_x, dim3(8192), dim3(256), 0, stream, x, xb);
    hipLaunchKernelGGL(prep_w, dim3(16, 16, 3), dim3(256), 0, stream, Wq, Wk, Wv, Wt);
    hipLaunchKernelGGL(qkv_gemm, dim3(256, 1, 3), dim3(512), 0, stream, xb, Wt, Q, K, Vt);
    hipLaunchKernelGGL(qk_pexp, dim3(272, B_), dim3(256), 0, stream, Q, K, P, lpart);
    hipLaunchKernelGGL(merge_il, dim3(NT_, B_), dim3(128), 0, stream, lpart, il);
    hipLaunchKernelGGL(pv_gemm, dim3(512), dim3(256), 0, stream, P, Vt, il, O);
}